// Round 2
// baseline (8949.563 us; speedup 1.0000x reference)
//
#include <hip/hip_runtime.h>
#include <math.h>

#define BB 256
#define TIN 32
#define TOUT 29
#define VDEC 72
#define EDIM 256
#define HDIM 256
#define DD 6
#define BH (BB*HDIM)
#define NBLK 256

typedef unsigned short u16;
typedef unsigned int u32;
typedef __bf16 bf16x8 __attribute__((ext_vector_type(8)));
typedef float f32x4 __attribute__((ext_vector_type(4)));
typedef u16 u16x8 __attribute__((ext_vector_type(8)));

__device__ __forceinline__ float sigmf(float x){ return 1.0f/(1.0f+__expf(-x)); }
__device__ __forceinline__ float tanhf_fast(float x){ return 1.0f - 2.0f/(1.0f+__expf(2.0f*x)); }
__device__ __forceinline__ u16 f2bf(float f){
  u32 u = __builtin_bit_cast(u32, f);
  u32 r = (u + 0x7fffu + ((u>>16)&1u)) >> 16;   // RNE; inputs finite
  return (u16)r;
}
__device__ __forceinline__ float bf2f(u16 s){
  u32 u = ((u32)s)<<16; return __builtin_bit_cast(float, u);
}
__device__ __forceinline__ bf16x8 ldbf8(const u16* p){
  u16x8 t = *(const u16x8*)p; return __builtin_bit_cast(bf16x8, t);
}
__device__ __forceinline__ f32x4 mfma16(bf16x8 a, bf16x8 b, f32x4 c){
  return __builtin_amdgcn_mfma_f32_16x16x32_bf16(a, b, c, 0, 0, 0);
}

// ---------------- shared memory union (39 KB max) ----------------
union SharedU {
  struct { u16 As[2][32][72]; u16 Ws[2][64][72]; float Gt[4][32][17]; } st;
  struct { float As[32][33]; float Ws[256][34]; } gm;
  struct { float s[512]; float p3[VDEC][3]; float lg[VDEC]; int tok; } fc;
};

// ---------------- grid barrier (all 256 blocks co-resident) ----------------
// Arrival: per-block slot (no atomic contention). Block 0's 256 threads poll the
// 256 slots, then flip the generation flag. Release/acquire at agent scope gives
// cross-XCD visibility (release emits L2 writeback; acquire fence invalidates).
__device__ __forceinline__ void gridbar(u32* __restrict__ arr, u32* __restrict__ gen,
                                        u32 g, int bid){
  __syncthreads();
  if (threadIdx.x == 0)
    __hip_atomic_store(&arr[bid], g, __ATOMIC_RELEASE, __HIP_MEMORY_SCOPE_AGENT);
  if (bid == 0){
    while (__hip_atomic_load(&arr[threadIdx.x], __ATOMIC_RELAXED, __HIP_MEMORY_SCOPE_AGENT) < g) {}
    __syncthreads();
    if (threadIdx.x == 0)
      __hip_atomic_store(gen, g, __ATOMIC_RELEASE, __HIP_MEMORY_SCOPE_AGENT);
  } else if (threadIdx.x == 0){
    while (__hip_atomic_load(gen, __ATOMIC_RELAXED, __HIP_MEMORY_SCOPE_AGENT) < g) {}
  }
  __builtin_amdgcn_fence(__ATOMIC_ACQUIRE, "agent");
  __syncthreads();
}

// ---------------- setup kernels ----------------
__global__ void fill_zero_u32(u32* __restrict__ p, int n){
  int i = blockIdx.x*256 + threadIdx.x;
  if (i < n) p[i] = 0u;
}

__global__ void init_out_kernel(float* __restrict__ out, int n){
  int i = blockIdx.x*256 + threadIdx.x;
  if (i >= n) return;
  float v = 0.0f;
  if (i < BB*VDEC && (i % VDEC) == 1) v = 1.0f;   // pred0 one-hot
  out[i] = v;
}

// bias2d[p][m][g] = (sum_l W2[m,l]) * b1[g] + b2[m]   (p: 0=a, 1=h, 2=c)
__global__ void bias2d_kernel(const float* __restrict__ W2a, const float* __restrict__ b1a, const float* __restrict__ b2a,
                              const float* __restrict__ W2h, const float* __restrict__ b1h, const float* __restrict__ b2h,
                              const float* __restrict__ W2c, const float* __restrict__ b1c, const float* __restrict__ b2c,
                              float* __restrict__ outp){
  int g = threadIdx.x;
  const float* W2[3] = {W2a, W2h, W2c};
  const float* b1[3] = {b1a, b1h, b1c};
  const float* b2[3] = {b2a, b2h, b2c};
  for (int p = 0; p < 3; p++)
    for (int m = 0; m < 6; m++){
      float s = 0.f;
      for (int l = 0; l < 6; l++) s += W2[p][m*6+l];
      outp[p*1536 + m*256 + g] = s * b1[p][g] + b2[p][m];
    }
}

__global__ void embed_enc_kernel(const int* __restrict__ input, const float* __restrict__ enc_emb,
                                 u16* __restrict__ x_emb){
  int i = blockIdx.x*256 + threadIdx.x;       // TIN*BB*EDIM threads
  int e = i & 255, b = (i >> 8) & 255, t = i >> 16;
  x_emb[i] = f2bf(enc_emb[(size_t)input[b*TIN + t]*EDIM + e]);
}

// pack fp32 weights -> bf16, row-permuted so each stage block's 64 rows are contiguous.
__global__ void pack_w_kernel(const float* __restrict__ Wih, const float* __restrict__ Whh,
                              u16* __restrict__ dst, int K1, int K){
  int k = blockIdx.x*256 + threadIdx.x;
  int row = blockIdx.y;
  int d = row >> 10, rr = row & 1023;
  int ht = rr >> 6, r = rr & 63;
  int g = (r>>4)*256 + ht*16 + (r&15);
  float v;
  if (k < K1) v = Wih[((size_t)d*1024 + g)*K1 + k];
  else        v = Whh[((size_t)d*1024 + g)*256 + (k - K1)];
  dst[(size_t)row*K + k] = f2bf(v);
}

// fused decoder stage-0 weights: W'[g, 0:512] = sum_o Wih0[g,o]*attn_W[o, 0:512]; cols 512:768 = Whh
__global__ void pack_wfused_kernel(const float* __restrict__ Wih0, const float* __restrict__ attn_W,
                                   const float* __restrict__ Whh, u16* __restrict__ dst){
  int k = blockIdx.x*256 + threadIdx.x;       // grid.x = 3 -> k in 0..767
  int row = blockIdx.y;                        // 0..2047
  int d = row >> 10, rr = row & 1023;
  int ht = rr >> 6, r = rr & 63;
  int g = (r>>4)*256 + ht*16 + (r&15);
  float v;
  if (k >= 512) v = Whh[((size_t)d*1024 + g)*256 + (k - 512)];
  else {
    const float* wr = Wih0 + ((size_t)d*1024 + g)*256;
    float s = 0.f;
    #pragma unroll 4
    for (int o = 0; o < 256; o++) s += wr[o] * attn_W[(size_t)o*512 + k];
    v = s;
  }
  dst[(size_t)row*768 + k] = f2bf(v);
}

// fused decoder stage-0 bias: b'[d,g] = dec_b[l=0,d,g] + sum_o Wih0[d,g,o]*attn_b[o]
__global__ void biasfold_kernel(const float* __restrict__ Wih0, const float* __restrict__ attn_b,
                                const float* __restrict__ dec_b, float* __restrict__ outb){
  int i = blockIdx.x*256 + threadIdx.x;  // 2048
  int d = i >> 10, g = i & 1023;
  const float* wr = Wih0 + ((size_t)d*1024 + g)*256;
  float s = dec_b[d*1024 + g];
  #pragma unroll 4
  for (int o = 0; o < 256; o++) s += wr[o]*attn_b[o];
  outb[i] = s;
}

// ---------------- phase: fused LSTM stage (bf16 MFMA) ----------------
// bid -> x = bid>>5 (batch tile), y = bid&31 -> d = y>>4, ht = y&15.
// Blocks sharing a weight slice differ by 32 in bid => same XCD (mod-8 round robin)
// => each 96KB slice stays resident in exactly one XCD L2.
template<int K1>
__device__ __forceinline__ void stage_phase(SharedU* shp, int bid,
    const u16* __restrict__ inp, const u16* __restrict__ Wpk, const float* __restrict__ bias_l,
    const u16* __restrict__ hR, u16* __restrict__ hW, float* __restrict__ cBuf,
    u16* __restrict__ inp_out, float* __restrict__ h_all_t, int l){
  auto& ss = shp->st;
  constexpr int K = K1 + 256;
  constexpr int NIT = K >> 6;
  int tid = threadIdx.x;
  int m_base = (bid >> 5) * 32;
  int y = bid & 31;
  int d = y >> 4, ht = y & 15;
  int idx = 2*l + d;
  const u16* Wblk = Wpk + (size_t)((d*16+ht)*64)*K;
  int q = tid >> 6, lane = tid & 63;
  int ar = tid >> 3, kp = (tid & 7)*8;
  const u16* aRow  = inp + (size_t)(m_base+ar)*K1 + kp;
  const u16* hRow  = hR + (size_t)idx*BH + (size_t)(m_base+ar)*HDIM + kp - K1;
  const u16* wRow0 = Wblk + (size_t)ar*K + kp;
  const u16* wRow1 = Wblk + (size_t)(ar+32)*K + kp;
  uint4 aP[2], w0P[2], w1P[2];
  #pragma unroll
  for (int pf = 0; pf < 2; pf++){
    int c0 = pf*64;
    const u16* ap = (c0 + kp < K1) ? aRow : hRow;
    aP[pf]  = *(const uint4*)(ap + c0);
    w0P[pf] = *(const uint4*)(wRow0 + c0);
    w1P[pf] = *(const uint4*)(wRow1 + c0);
  }
  f32x4 acc0 = {0.f,0.f,0.f,0.f}, acc1 = {0.f,0.f,0.f,0.f};
  #pragma unroll
  for (int i = 0; i < NIT; i++){
    int p = i & 1;
    *(uint4*)&ss.As[p][ar][kp]     = aP[p];
    *(uint4*)&ss.Ws[p][ar][kp]     = w0P[p];
    *(uint4*)&ss.Ws[p][ar+32][kp]  = w1P[p];
    int c0n = (i+2) << 6;
    if (c0n < K){
      const u16* ap = (c0n + kp < K1) ? aRow : hRow;
      aP[p]  = *(const uint4*)(ap + c0n);
      w0P[p] = *(const uint4*)(wRow0 + c0n);
      w1P[p] = *(const uint4*)(wRow1 + c0n);
    }
    __syncthreads();
    #pragma unroll
    for (int kh = 0; kh < 2; kh++){
      int kb = kh*32 + (lane>>4)*8;
      bf16x8 a0 = ldbf8(&ss.As[p][lane & 15][kb]);
      bf16x8 a1 = ldbf8(&ss.As[p][16 + (lane & 15)][kb]);
      bf16x8 bq = ldbf8(&ss.Ws[p][q*16 + (lane & 15)][kb]);
      acc0 = mfma16(a0, bq, acc0);
      acc1 = mfma16(a1, bq, acc1);
    }
  }
  int hh = lane & 15, rq = lane >> 4;
  #pragma unroll
  for (int r = 0; r < 4; r++){
    ss.Gt[q][rq*4 + r][hh]      = acc0[r];
    ss.Gt[q][16 + rq*4 + r][hh] = acc1[r];
  }
  __syncthreads();
  const float* bias = bias_l + d*1024;
  #pragma unroll
  for (int it = 0; it < 2; it++){
    int id = tid + it*256;
    int bb = id >> 4, h2 = id & 15;
    int b = m_base + bb, h = ht*16 + h2;
    float iv = ss.Gt[0][bb][h2] + bias[h];
    float fv = ss.Gt[1][bb][h2] + bias[256 + h];
    float gv = ss.Gt[2][bb][h2] + bias[512 + h];
    float ov = ss.Gt[3][bb][h2] + bias[768 + h];
    size_t off = (size_t)idx*BH + (size_t)b*HDIM + h;
    float cold = cBuf[off];
    float cc = sigmf(fv)*cold + sigmf(iv)*tanhf_fast(gv);
    float hv = sigmf(ov)*tanhf_fast(cc);
    cBuf[off] = cc;
    u16 hb = f2bf(hv);
    hW[off] = hb;
    inp_out[(size_t)b*512 + d*HDIM + h] = hb;
    if (h_all_t) h_all_t[off] = hv;
  }
}

// ---------------- phase: 6x6 layer-mix (block-stride) ----------------
__device__ __forceinline__ void mix_phase(int bid, const float* __restrict__ inp,
    float* __restrict__ outp, const float* __restrict__ W2, int n){
  for (int i = bid*256 + (int)threadIdx.x; i < n; i += NBLK*256){
    int h = i & 255, b = (i >> 8) & 255, t = i >> 16;
    size_t base2 = ((size_t)t*6)*BH + (size_t)b*256 + h;
    float v[6];
    #pragma unroll
    for (int l = 0; l < 6; l++) v[l] = inp[base2 + (size_t)l*BH];
    #pragma unroll
    for (int m = 0; m < 6; m++){
      float s = 0.f;
      #pragma unroll
      for (int l = 0; l < 6; l++) s += W2[m*6+l]*v[l];
      outp[base2 + (size_t)m*BH] = s;
    }
  }
}

// ---------------- phase: fp32 gemm tile, C[M,256] = A[M,256]@W^T + bias ----------------
__device__ __forceinline__ void gemm_tile(SharedU* shp, int m_base,
    const float* __restrict__ A, float* __restrict__ C, const float* __restrict__ W,
    const float* __restrict__ bias2d, u16* __restrict__ Cbf){
  auto& sg = shp->gm;
  int tid = threadIdx.x;
  int rg = tid >> 5, cg = tid & 31;
  float acc[4][8];
  #pragma unroll
  for (int i=0;i<4;i++)
    #pragma unroll
    for (int j=0;j<8;j++) acc[i][j]=0.f;
  for (int k0 = 0; k0 < 256; k0 += 32){
    #pragma unroll
    for (int p=0;p<4;p++) sg.As[rg + p*8][cg] = A[(size_t)(m_base + rg + p*8)*256 + k0 + cg];
    #pragma unroll
    for (int p=0;p<32;p++) sg.Ws[rg + p*8][cg] = W[(size_t)(rg + p*8)*256 + k0 + cg];
    __syncthreads();
    #pragma unroll
    for (int kk=0; kk<32; kk++){
      float a[4], w[8];
      #pragma unroll
      for (int i=0;i<4;i++) a[i] = sg.As[rg*4+i][kk];
      #pragma unroll
      for (int j=0;j<8;j++) w[j] = sg.Ws[cg*8+j][kk];
      #pragma unroll
      for (int i=0;i<4;i++)
        #pragma unroll
        for (int j=0;j<8;j++) acc[i][j] += a[i]*w[j];
    }
    __syncthreads();
  }
  #pragma unroll
  for (int i=0;i<4;i++){
    int row = m_base + rg*4 + i;
    int bm = (row >> 8) % 6;
    #pragma unroll
    for (int j=0;j<8;j++){
      float v = acc[i][j] + bias2d[bm*256 + cg*8 + j];
      if (C)   C[(size_t)row*256 + cg*8 + j] = v;
      if (Cbf) Cbf[(size_t)row*256 + cg*8 + j] = f2bf(v);
    }
  }
}

// ---------------- phase: attention ctx + fc(prev) + token embed ----------------
__device__ __forceinline__ void attn_phase(SharedU* shp, int b, int step,
    const u16* __restrict__ hR, const u16* __restrict__ eo, u16* __restrict__ cat,
    const int* __restrict__ tf, float* __restrict__ attn_out,
    const int* __restrict__ target, float* __restrict__ outp,
    const float* __restrict__ dec_emb, const u16* __restrict__ top,
    const float* __restrict__ fc_W, const float* __restrict__ fc_b){
  auto& sf = shp->fc;
  int tid = threadIdx.x;
  // fc for previous step's logits (3-way k-split, 216 active threads)
  if (step > 0){
    sf.s[tid]       = bf2f(top[(size_t)b*512 + tid]);
    sf.s[tid + 256] = bf2f(top[(size_t)b*512 + 256 + tid]);
    __syncthreads();
    if (tid < 3*VDEC){
      int v = tid/3, part = tid - 3*(tid/3);
      int k0 = part*171, k1 = (part==2) ? 512 : (k0+171);
      const float* wr = fc_W + (size_t)v*512;
      float a = 0.f;
      for (int k = k0; k < k1; k++) a += sf.s[k]*wr[k];
      sf.p3[v][part] = a;
    }
    __syncthreads();
    if (tid < VDEC){
      float a = fc_b[tid] + sf.p3[tid][0] + sf.p3[tid][1] + sf.p3[tid][2];
      outp[((size_t)step*BB + b)*VDEC + tid] = a;
      sf.lg[tid] = a;
    }
    __syncthreads();
  }
  // token select + embed
  int tok;
  if (tf[0]) tok = target[b*TOUT + step];
  else if (step == 0) tok = 1;
  else {
    if (tid == 0){
      int bi = 0; float bv = sf.lg[0];
      for (int v = 1; v < VDEC; v++){ float x = sf.lg[v]; if (x > bv){ bv = x; bi = v; } }
      sf.tok = bi;
    }
    __syncthreads();
    tok = sf.tok;
  }
  cat[(size_t)b*512 + tid] = f2bf(dec_emb[(size_t)tok*EDIM + tid]);
  // ctx (softmax over source time, per dir, averaged)
  int hc = tid;
  bool wa = (tf[0] == 0);
  float acc = 0.f;
  for (int d = 0; d < DD; d++){
    float hv = bf2f(hR[(size_t)d*BH + (size_t)b*256 + hc]);
    const u16* ep = eo + (size_t)d*BH + (size_t)b*256 + hc;
    float se = 0.f, ac = 0.f;
    #pragma unroll 8
    for (int t = 0; t < TIN; t++){
      float ev = bf2f(ep[(size_t)t*(DD*BH)]);
      float e = __expf(hv*ev);
      se += e; ac += e*ev;
    }
    acc += ac/se;
    if (wa){
      float inv = 1.f/se;
      for (int t = 0; t < TIN; t++){
        float ev = bf2f(ep[(size_t)t*(DD*BH)]);
        atomicAdd(&attn_out[(((size_t)(step+1)*TIN + t)*DD + d)*BB + b], __expf(hv*ev)*inv);
      }
    }
  }
  cat[(size_t)b*512 + 256 + hc] = f2bf(acc*(1.0f/6.0f));
}

__device__ __forceinline__ void fc_final_phase(SharedU* shp, int b,
    const u16* __restrict__ top, const float* __restrict__ fc_W,
    const float* __restrict__ fc_b, float* __restrict__ outp){
  auto& sf = shp->fc;
  int tid = threadIdx.x;
  sf.s[tid]       = bf2f(top[(size_t)b*512 + tid]);
  sf.s[tid + 256] = bf2f(top[(size_t)b*512 + 256 + tid]);
  __syncthreads();
  if (tid < 3*VDEC){
    int v = tid/3, part = tid - 3*(tid/3);
    int k0 = part*171, k1 = (part==2) ? 512 : (k0+171);
    const float* wr = fc_W + (size_t)v*512;
    float a = 0.f;
    for (int k = k0; k < k1; k++) a += sf.s[k]*wr[k];
    sf.p3[v][part] = a;
  }
  __syncthreads();
  if (tid < VDEC){
    float a = fc_b[tid] + sf.p3[tid][0] + sf.p3[tid][1] + sf.p3[tid][2];
    outp[((size_t)(TOUT-1)*BB + b)*VDEC + tid] = a;
  }
}

// ---------------- THE megakernel ----------------
__global__ __launch_bounds__(256, 1) void mega_kernel(
    const int* __restrict__ target, const int* __restrict__ tf,
    const float* __restrict__ dec_emb, const u16* __restrict__ x_emb,
    const u16* __restrict__ wp_e0, const u16* __restrict__ wp_e1, const u16* __restrict__ wp_e2,
    const u16* __restrict__ wp_d0f, const u16* __restrict__ wp_d1, const u16* __restrict__ wp_d2,
    const float* __restrict__ enc_b, const float* __restrict__ dec_b, const float* __restrict__ fb0,
    const float* __restrict__ lin_h_W1, const float* __restrict__ lin_c_W1, const float* __restrict__ lin_a_W1,
    const float* __restrict__ lin_h_W2, const float* __restrict__ lin_c_W2, const float* __restrict__ lin_a_W2,
    const float* __restrict__ bias2d,
    const float* __restrict__ fc_W, const float* __restrict__ fc_b,
    float* __restrict__ out,
    float* __restrict__ h_all, float* __restrict__ tmp6, float* __restrict__ tmp6c,
    float* __restrict__ dec_c, u16* __restrict__ enc_hA, float* __restrict__ enc_c,
    u16* __restrict__ enc_hB, u16* __restrict__ dec_hA, u16* __restrict__ dec_hB,
    u16* __restrict__ bufA, u16* __restrict__ bufB, u16* __restrict__ cat,
    u16* __restrict__ eo_bf, u32* __restrict__ bar_arr, u32* __restrict__ bar_gen)
{
  __shared__ SharedU sh;
  int bid = blockIdx.x;
  u32 g = 0;

  // -------- encoder: 32 timesteps x 3 stages --------
  for (int t = 0; t < TIN; t++){
    const u16* hRb = (t & 1) ? enc_hB : enc_hA;
    u16*       hWb = (t & 1) ? enc_hA : enc_hB;
    float* hat = h_all + (size_t)t*DD*BH;
    stage_phase<256>(&sh, bid, x_emb + (size_t)t*BB*EDIM, wp_e0, enc_b,        hRb, hWb, enc_c, bufA, hat, 0);
    gridbar(bar_arr, bar_gen, ++g, bid);
    stage_phase<512>(&sh, bid, bufA,                      wp_e1, enc_b + 2048, hRb, hWb, enc_c, bufB, hat, 1);
    gridbar(bar_arr, bar_gen, ++g, bid);
    stage_phase<512>(&sh, bid, bufB,                      wp_e2, enc_b + 4096, hRb, hWb, enc_c, bufA, hat, 2);
    gridbar(bar_arr, bar_gen, ++g, bid);
  }

  // -------- bridges --------
  mix_phase(bid, h_all + (size_t)31*DD*BH, tmp6,  lin_h_W2, BH);
  mix_phase(bid, enc_c,                    tmp6c, lin_c_W2, BH);
  gridbar(bar_arr, bar_gen, ++g, bid);
  // 96 tiles: 0..47 h-bridge, 48..95 c-bridge (one tile per block)
  if (bid < 48)       gemm_tile(&sh, bid*32,      tmp6,  nullptr, lin_h_W1, bias2d + 1536, dec_hA);
  else if (bid < 96)  gemm_tile(&sh, (bid-48)*32, tmp6c, dec_c,   lin_c_W1, bias2d + 3072, nullptr);
  gridbar(bar_arr, bar_gen, ++g, bid);
  mix_phase(bid, h_all, h_all, lin_a_W2, TIN*BH);
  gridbar(bar_arr, bar_gen, ++g, bid);
  for (int tile = bid; tile < 1536; tile += NBLK)
    gemm_tile(&sh, tile*32, h_all, nullptr, lin_a_W1, bias2d, eo_bf);
  gridbar(bar_arr, bar_gen, ++g, bid);

  // -------- decoder: 28 steps x (attn+fc | stage0 | stage1 | stage2) --------
  float* attn_out = out + (size_t)TOUT*BB*VDEC;
  for (int i = 0; i < TOUT-1; i++){
    const u16* hRb = (i & 1) ? dec_hB : dec_hA;
    u16*       hWb = (i & 1) ? dec_hA : dec_hB;
    attn_phase(&sh, bid, i, hRb, eo_bf, cat, tf, attn_out, target, out, dec_emb, bufA, fc_W, fc_b);
    gridbar(bar_arr, bar_gen, ++g, bid);
    stage_phase<512>(&sh, bid, cat,  wp_d0f, fb0,          hRb, hWb, dec_c, bufA, nullptr, 0);
    gridbar(bar_arr, bar_gen, ++g, bid);
    stage_phase<512>(&sh, bid, bufA, wp_d1,  dec_b + 2048, hRb, hWb, dec_c, bufB, nullptr, 1);
    gridbar(bar_arr, bar_gen, ++g, bid);
    stage_phase<512>(&sh, bid, bufB, wp_d2,  dec_b + 4096, hRb, hWb, dec_c, bufA, nullptr, 2);
    gridbar(bar_arr, bar_gen, ++g, bid);
  }
  fc_final_phase(&sh, bid, bufA, fc_W, fc_b, out);
}

// =====================================================================

extern "C" void kernel_launch(void* const* d_in, const int* in_sizes, int n_in,
                              void* d_out, int out_size, void* d_ws, size_t ws_size,
                              hipStream_t stream){
  (void)in_sizes; (void)n_in; (void)out_size; (void)ws_size;
  const int*   input    = (const int*)d_in[0];
  const int*   target   = (const int*)d_in[1];
  const int*   tf       = (const int*)d_in[2];
  const float* enc_emb  = (const float*)d_in[3];
  const float* dec_emb  = (const float*)d_in[4];
  const float* enc_Wih0 = (const float*)d_in[5];
  const float* enc_Wih1 = (const float*)d_in[6];
  const float* enc_Whh  = (const float*)d_in[7];
  const float* enc_b    = (const float*)d_in[8];
  const float* dec_Wih0 = (const float*)d_in[9];
  const float* dec_Wih1 = (const float*)d_in[10];
  const float* dec_Whh  = (const float*)d_in[11];
  const float* dec_b    = (const float*)d_in[12];
  const float* lin_h_W1 = (const float*)d_in[13];
  const float* lin_h_b1 = (const float*)d_in[14];
  const float* lin_h_W2 = (const float*)d_in[15];
  const float* lin_h_b2 = (const float*)d_in[16];
  const float* lin_c_W1 = (const float*)d_in[17];
  const float* lin_c_b1 = (const float*)d_in[18];
  const float* lin_c_W2 = (const float*)d_in[19];
  const float* lin_c_b2 = (const float*)d_in[20];
  const float* lin_a_W1 = (const float*)d_in[21];
  const float* lin_a_b1 = (const float*)d_in[22];
  const float* lin_a_W2 = (const float*)d_in[23];
  const float* lin_a_b2 = (const float*)d_in[24];
  const float* attn_W   = (const float*)d_in[25];
  const float* attn_b   = (const float*)d_in[26];
  const float* fc_W     = (const float*)d_in[27];
  const float* fc_b     = (const float*)d_in[28];
  float* out = (float*)d_out;

  char* base = (char*)d_ws;
  size_t off = 0;
  auto alloc = [&](size_t bytes)->char*{
    char* p = base + off; off += (bytes + 255) & ~(size_t)255; return p;
  };
  float* h_all  = (float*)alloc(sizeof(float)*(size_t)TIN*DD*BH);
  float* tmp6   = (float*)alloc(sizeof(float)*(size_t)DD*BH);
  float* tmp6c  = (float*)alloc(sizeof(float)*(size_t)DD*BH);
  float* dec_c  = (float*)alloc(sizeof(float)*(size_t)DD*BH);
  float* bias2d = (float*)alloc(sizeof(float)*3*6*256);
  // zero block: enc_hA (bf16) + enc_c (fp32), contiguous
  u16*   enc_hA = (u16*)alloc(sizeof(u16)*(size_t)DD*BH + sizeof(float)*(size_t)DD*BH);
  float* enc_c  = (float*)(enc_hA + (size_t)DD*BH);
  u16* enc_hB = (u16*)alloc(sizeof(u16)*(size_t)DD*BH);
  u16* dec_hA = (u16*)alloc(sizeof(u16)*(size_t)DD*BH);
  u16* dec_hB = (u16*)alloc(sizeof(u16)*(size_t)DD*BH);
  u16* x_emb  = (u16*)alloc(sizeof(u16)*(size_t)TIN*BB*EDIM);
  u16* bufA   = (u16*)alloc(sizeof(u16)*(size_t)BB*512);
  u16* bufB   = (u16*)alloc(sizeof(u16)*(size_t)BB*512);
  u16* cat    = (u16*)alloc(sizeof(u16)*(size_t)BB*512);       // [emb | ctx]
  u16* eo_bf  = (u16*)alloc(sizeof(u16)*(size_t)TIN*DD*BH);    // bf16 encoder_outputs
  u16* wp_e0  = (u16*)alloc(sizeof(u16)*(size_t)2048*512);
  u16* wp_e1  = (u16*)alloc(sizeof(u16)*(size_t)2048*768);
  u16* wp_e2  = (u16*)alloc(sizeof(u16)*(size_t)2048*768);
  u16* wp_d0f = (u16*)alloc(sizeof(u16)*(size_t)2048*768);     // fused attn_W . Wih0 | Whh
  u16* wp_d1  = (u16*)alloc(sizeof(u16)*(size_t)2048*768);
  u16* wp_d2  = (u16*)alloc(sizeof(u16)*(size_t)2048*768);
  float* fb0  = (float*)alloc(sizeof(float)*2048);             // fused stage-0 bias
  u32* barblk = (u32*)alloc(sizeof(u32)*512);                  // [0..255] arr, [256] gen

  const int outn = TOUT*BB*VDEC + TOUT*TIN*DD*BB;
  init_out_kernel<<<(outn+255)/256, 256, 0, stream>>>(out, outn);
  fill_zero_u32<<<(DD*BH*6/4 + 255)/256, 256, 0, stream>>>((u32*)enc_hA, DD*BH*6/4);
  fill_zero_u32<<<2, 256, 0, stream>>>(barblk, 512);
  bias2d_kernel<<<1, 256, 0, stream>>>(lin_a_W2, lin_a_b1, lin_a_b2,
                                       lin_h_W2, lin_h_b1, lin_h_b2,
                                       lin_c_W2, lin_c_b1, lin_c_b2, bias2d);
  embed_enc_kernel<<<(TIN*BB*EDIM)/256, 256, 0, stream>>>(input, enc_emb, x_emb);
  pack_w_kernel<<<dim3(2,2048), 256, 0, stream>>>(enc_Wih0, enc_Whh,                       wp_e0, 256, 512);
  pack_w_kernel<<<dim3(3,2048), 256, 0, stream>>>(enc_Wih1, enc_Whh + 2*1024*256,          wp_e1, 512, 768);
  pack_w_kernel<<<dim3(3,2048), 256, 0, stream>>>(enc_Wih1 + (size_t)2*1024*512, enc_Whh + 4*1024*256, wp_e2, 512, 768);
  pack_wfused_kernel<<<dim3(3,2048), 256, 0, stream>>>(dec_Wih0, attn_W, dec_Whh,          wp_d0f);
  biasfold_kernel<<<8, 256, 0, stream>>>(dec_Wih0, attn_b, dec_b, fb0);
  pack_w_kernel<<<dim3(3,2048), 256, 0, stream>>>(dec_Wih1, dec_Whh + 2*1024*256,          wp_d1, 512, 768);
  pack_w_kernel<<<dim3(3,2048), 256, 0, stream>>>(dec_Wih1 + (size_t)2*1024*512, dec_Whh + 4*1024*256, wp_d2, 512, 768);

  mega_kernel<<<NBLK, 256, 0, stream>>>(
      target, tf, dec_emb, x_emb,
      wp_e0, wp_e1, wp_e2, wp_d0f, wp_d1, wp_d2,
      enc_b, dec_b, fb0,
      lin_h_W1, lin_c_W1, lin_a_W1, lin_h_W2, lin_c_W2, lin_a_W2,
      bias2d, fc_W, fc_b, out,
      h_all, tmp6, tmp6c, dec_c, enc_hA, enc_c, enc_hB, dec_hA, dec_hB,
      bufA, bufB, cat, eo_bf, barblk, barblk + 256);
}

// Round 3
// 4528.502 us; speedup vs baseline: 1.9763x; 1.9763x over previous
//
#include <hip/hip_runtime.h>
#include <math.h>

#define BB 256
#define TIN 32
#define TOUT 29
#define VDEC 72
#define EDIM 256
#define HDIM 256
#define DD 6
#define BH (BB*HDIM)
#define NBLK 256

typedef unsigned short u16;
typedef unsigned int u32;
typedef __bf16 bf16x8 __attribute__((ext_vector_type(8)));
typedef float f32x4 __attribute__((ext_vector_type(4)));
typedef u16 u16x8 __attribute__((ext_vector_type(8)));

__device__ __forceinline__ float sigmf(float x){ return 1.0f/(1.0f+__expf(-x)); }
__device__ __forceinline__ float tanhf_fast(float x){ return 1.0f - 2.0f/(1.0f+__expf(2.0f*x)); }
__device__ __forceinline__ u16 f2bf(float f){
  u32 u = __builtin_bit_cast(u32, f);
  u32 r = (u + 0x7fffu + ((u>>16)&1u)) >> 16;   // RNE; inputs finite
  return (u16)r;
}
__device__ __forceinline__ float bf2f(u16 s){
  u32 u = ((u32)s)<<16; return __builtin_bit_cast(float, u);
}
__device__ __forceinline__ bf16x8 ldbf8(const u16* p){
  u16x8 t = *(const u16x8*)p; return __builtin_bit_cast(bf16x8, t);
}
// volatile = sc0 = L1-bypass: required for cross-block (same-XCD) recurrent data
__device__ __forceinline__ bf16x8 ldbf8v(const u16* p){
  u16x8 t = *(const volatile u16x8*)p; return __builtin_bit_cast(bf16x8, t);
}
__device__ __forceinline__ float ldbfv(const u16* p){ return bf2f(*(const volatile u16*)p); }
__device__ __forceinline__ f32x4 mfma16(bf16x8 a, bf16x8 b, f32x4 c){
  return __builtin_amdgcn_mfma_f32_16x16x32_bf16(a, b, c, 0, 0, 0);
}

// ---------------- shared memory union ----------------
union SharedU {
  struct { float Gt[4][32][17]; } st;
  struct { float As[32][33]; float Ws[256][34]; } gm;
  struct { float s[512]; float p3[VDEC][3]; float lg[VDEC]; int tok; } fc;
};

// ---------------- grid barrier ----------------
// fast: pure flag protocol, NO cache maintenance (all plain data is XCD-local;
//       producer stores are in L2 by the entry __syncthreads' vmcnt drain;
//       consumers use volatile/sc0 loads that read L2 directly).
// slow: round-2 semantics (full agent release/acquire) — correct for any mapping.
__device__ __forceinline__ void gridbar(u32* arr, u32* gen, u32 g, int bid, bool fast){
  __syncthreads();
  if (fast){
    if (threadIdx.x == 0)
      __hip_atomic_store(&arr[bid], g, __ATOMIC_RELAXED, __HIP_MEMORY_SCOPE_AGENT);
    if (bid == 0){
      while (__hip_atomic_load(&arr[threadIdx.x], __ATOMIC_RELAXED, __HIP_MEMORY_SCOPE_AGENT) < g) {}
      __syncthreads();
      if (threadIdx.x == 0)
        __hip_atomic_store(gen, g, __ATOMIC_RELAXED, __HIP_MEMORY_SCOPE_AGENT);
    } else if (threadIdx.x == 0){
      while (__hip_atomic_load(gen, __ATOMIC_RELAXED, __HIP_MEMORY_SCOPE_AGENT) < g) {}
    }
  } else {
    if (threadIdx.x == 0)
      __hip_atomic_store(&arr[bid], g, __ATOMIC_RELEASE, __HIP_MEMORY_SCOPE_AGENT);
    if (bid == 0){
      while (__hip_atomic_load(&arr[threadIdx.x], __ATOMIC_RELAXED, __HIP_MEMORY_SCOPE_AGENT) < g) {}
      __syncthreads();
      if (threadIdx.x == 0)
        __hip_atomic_store(gen, g, __ATOMIC_RELEASE, __HIP_MEMORY_SCOPE_AGENT);
    } else if (threadIdx.x == 0){
      while (__hip_atomic_load(gen, __ATOMIC_RELAXED, __HIP_MEMORY_SCOPE_AGENT) < g) {}
    }
    __builtin_amdgcn_fence(__ATOMIC_ACQUIRE, "agent");
  }
  __syncthreads();
}

// ---------------- setup kernels ----------------
__global__ void fill_zero_u32(u32* __restrict__ p, int n){
  int i = blockIdx.x*256 + threadIdx.x;
  if (i < n) p[i] = 0u;
}

__global__ void init_out_kernel(float* __restrict__ out, int n){
  int i = blockIdx.x*256 + threadIdx.x;
  if (i >= n) return;
  float v = 0.0f;
  if (i < BB*VDEC && (i % VDEC) == 1) v = 1.0f;   // pred0 one-hot
  out[i] = v;
}

// bias2d[p][m][g] = (sum_l W2[m,l]) * b1[g] + b2[m]   (p: 0=a, 1=h, 2=c)
__global__ void bias2d_kernel(const float* __restrict__ W2a, const float* __restrict__ b1a, const float* __restrict__ b2a,
                              const float* __restrict__ W2h, const float* __restrict__ b1h, const float* __restrict__ b2h,
                              const float* __restrict__ W2c, const float* __restrict__ b1c, const float* __restrict__ b2c,
                              float* __restrict__ outp){
  int g = threadIdx.x;
  const float* W2[3] = {W2a, W2h, W2c};
  const float* b1[3] = {b1a, b1h, b1c};
  const float* b2[3] = {b2a, b2h, b2c};
  for (int p = 0; p < 3; p++)
    for (int m = 0; m < 6; m++){
      float s = 0.f;
      for (int l = 0; l < 6; l++) s += W2[p][m*6+l];
      outp[p*1536 + m*256 + g] = s * b1[p][g] + b2[p][m];
    }
}

__global__ void embed_enc_kernel(const int* __restrict__ input, const float* __restrict__ enc_emb,
                                 u16* __restrict__ x_emb){
  int i = blockIdx.x*256 + threadIdx.x;       // TIN*BB*EDIM threads
  int e = i & 255, b = (i >> 8) & 255, t = i >> 16;
  x_emb[i] = f2bf(enc_emb[(size_t)input[b*TIN + t]*EDIM + e]);
}

// pack fp32 weights -> bf16, row-permuted so each stage block's 64 rows are contiguous.
__global__ void pack_w_kernel(const float* __restrict__ Wih, const float* __restrict__ Whh,
                              u16* __restrict__ dst, int K1, int K){
  int k = blockIdx.x*256 + threadIdx.x;
  int row = blockIdx.y;
  int d = row >> 10, rr = row & 1023;
  int ht = rr >> 6, r = rr & 63;
  int g = (r>>4)*256 + ht*16 + (r&15);
  float v;
  if (k < K1) v = Wih[((size_t)d*1024 + g)*K1 + k];
  else        v = Whh[((size_t)d*1024 + g)*256 + (k - K1)];
  dst[(size_t)row*K + k] = f2bf(v);
}

// fused decoder stage-0 weights: W'[g,0:512] = sum_o Wih0[g,o]*attn_W[o,0:512]; cols 512:768 = Whh
__global__ void pack_wfused_kernel(const float* __restrict__ Wih0, const float* __restrict__ attn_W,
                                   const float* __restrict__ Whh, u16* __restrict__ dst){
  int k = blockIdx.x*256 + threadIdx.x;       // grid.x = 3 -> k in 0..767
  int row = blockIdx.y;                        // 0..2047
  int d = row >> 10, rr = row & 1023;
  int ht = rr >> 6, r = rr & 63;
  int g = (r>>4)*256 + ht*16 + (r&15);
  float v;
  if (k >= 512) v = Whh[((size_t)d*1024 + g)*256 + (k - 512)];
  else {
    const float* wr = Wih0 + ((size_t)d*1024 + g)*256;
    float s = 0.f;
    #pragma unroll 4
    for (int o = 0; o < 256; o++) s += wr[o] * attn_W[(size_t)o*512 + k];
    v = s;
  }
  dst[(size_t)row*768 + k] = f2bf(v);
}

// fused decoder stage-0 bias: b'[d,g] = dec_b[l=0,d,g] + sum_o Wih0[d,g,o]*attn_b[o]
__global__ void biasfold_kernel(const float* __restrict__ Wih0, const float* __restrict__ attn_b,
                                const float* __restrict__ dec_b, float* __restrict__ outb){
  int i = blockIdx.x*256 + threadIdx.x;  // 2048
  int d = i >> 10, g = i & 1023;
  const float* wr = Wih0 + ((size_t)d*1024 + g)*256;
  float s = dec_b[d*1024 + g];
  #pragma unroll 4
  for (int o = 0; o < 256; o++) s += wr[o]*attn_b[o];
  outb[i] = s;
}

// ---------------- phase: fused LSTM stage (bf16 MFMA, direct global->reg fragments) ----------------
// block (mt, y): batch rows [mt*32, mt*32+32), weight slice (d=y>>4, ht=y&15).
// All recurrent inputs (inp, hR) are produced on the SAME XCD (mt == XCC_ID in fast mode).
template<int K1>
__device__ __forceinline__ void stage_phase(SharedU* shp, int mt, int y,
    const u16* __restrict__ inp, const u16* __restrict__ Wpk, const float* __restrict__ bias_l,
    const u16* __restrict__ hR, u16* __restrict__ hW, float* __restrict__ cBuf,
    u16* __restrict__ inp_out, float* __restrict__ h_all_t, int l){
  auto& ss = shp->st;
  constexpr int K = K1 + 256;
  constexpr int NIT = K >> 6;
  int tid = threadIdx.x;
  int m_base = mt*32;
  int d = y >> 4, ht = y & 15;
  int idx = 2*l + d;
  int q = tid >> 6, lane = tid & 63;
  int r = lane & 15, lq = lane >> 4;
  // fragment base pointers: lane (r, lq) of wave q
  const u16* a0p = inp + (size_t)(m_base + r)*K1 + lq*8;
  const u16* a1p = a0p + (size_t)16*K1;
  const u16* h0p = hR + (size_t)idx*BH + (size_t)(m_base + r)*HDIM + lq*8;
  const u16* h1p = h0p + 16*HDIM;
  const u16* wp  = Wpk + (size_t)((d*16+ht)*64 + q*16 + r)*K + lq*8;
  f32x4 acc0 = {0.f,0.f,0.f,0.f}, acc1 = {0.f,0.f,0.f,0.f};
  #pragma unroll
  for (int i = 0; i < NIT; i++){
    #pragma unroll
    for (int kh = 0; kh < 2; kh++){
      const int col = i*64 + kh*32;            // compile-time after unroll
      bf16x8 a0, a1;
      if (col < K1){
        a0 = ldbf8v(a0p + col);
        a1 = ldbf8v(a1p + col);
      } else {
        a0 = ldbf8v(h0p + (col - K1));
        a1 = ldbf8v(h1p + (col - K1));
      }
      bf16x8 bq = ldbf8(wp + col);             // weights read-only: L1-cached
      acc0 = mfma16(a0, bq, acc0);
      acc1 = mfma16(a1, bq, acc1);
    }
  }
  // gate exchange across waves (i,f,g,o live in different waves' accumulators)
  #pragma unroll
  for (int rr = 0; rr < 4; rr++){
    ss.Gt[q][lq*4 + rr][r]      = acc0[rr];
    ss.Gt[q][16 + lq*4 + rr][r] = acc1[rr];
  }
  __syncthreads();
  const float* bias = bias_l + d*1024;
  #pragma unroll
  for (int it = 0; it < 2; it++){
    int id = tid + it*256;
    int bb = id >> 4, h2 = id & 15;
    int b = m_base + bb, h = ht*16 + h2;
    float iv = ss.Gt[0][bb][h2] + bias[h];
    float fv = ss.Gt[1][bb][h2] + bias[256 + h];
    float gv = ss.Gt[2][bb][h2] + bias[512 + h];
    float ov = ss.Gt[3][bb][h2] + bias[768 + h];
    size_t off = (size_t)idx*BH + (size_t)b*HDIM + h;
    float cold = cBuf[off];                    // own slice: self-coherent via L1
    float cc = sigmf(fv)*cold + sigmf(iv)*tanhf_fast(gv);
    float hv = sigmf(ov)*tanhf_fast(cc);
    cBuf[off] = cc;
    u16 hb = f2bf(hv);
    hW[off] = hb;
    inp_out[(size_t)b*512 + d*HDIM + h] = hb;
    if (h_all_t) h_all_t[off] = hv;
  }
}

// ---------------- phase: 6x6 layer-mix, XCD-local (b = mt*32+y, h = tid) ----------------
__device__ __forceinline__ void mix_phase_local(int mt, int y, const float* __restrict__ inp,
    float* __restrict__ outp, const float* __restrict__ W2, int nt){
  int b = mt*32 + y, h = threadIdx.x;
  for (int t = 0; t < nt; t++){
    size_t base2 = ((size_t)t*6)*BH + (size_t)b*256 + h;
    float v[6];
    #pragma unroll
    for (int l = 0; l < 6; l++) v[l] = inp[base2 + (size_t)l*BH];
    #pragma unroll
    for (int m = 0; m < 6; m++){
      float s = 0.f;
      #pragma unroll
      for (int l = 0; l < 6; l++) s += W2[m*6+l]*v[l];
      outp[base2 + (size_t)m*BH] = s;
    }
  }
}

// ---------------- phase: fp32 gemm tile, C[M,256] = A[M,256]@W^T + bias ----------------
__device__ __forceinline__ void gemm_tile(SharedU* shp, int m_base,
    const float* __restrict__ A, float* __restrict__ C, const float* __restrict__ W,
    const float* __restrict__ bias2d, u16* __restrict__ Cbf){
  auto& sg = shp->gm;
  int tid = threadIdx.x;
  int rg = tid >> 5, cg = tid & 31;
  float acc[4][8];
  #pragma unroll
  for (int i=0;i<4;i++)
    #pragma unroll
    for (int j=0;j<8;j++) acc[i][j]=0.f;
  for (int k0 = 0; k0 < 256; k0 += 32){
    #pragma unroll
    for (int p=0;p<4;p++) sg.As[rg + p*8][cg] = *(const volatile float*)&A[(size_t)(m_base + rg + p*8)*256 + k0 + cg];
    #pragma unroll
    for (int p=0;p<32;p++) sg.Ws[rg + p*8][cg] = W[(size_t)(rg + p*8)*256 + k0 + cg];
    __syncthreads();
    #pragma unroll
    for (int kk=0; kk<32; kk++){
      float a[4], w[8];
      #pragma unroll
      for (int i=0;i<4;i++) a[i] = sg.As[rg*4+i][kk];
      #pragma unroll
      for (int j=0;j<8;j++) w[j] = sg.Ws[cg*8+j][kk];
      #pragma unroll
      for (int i=0;i<4;i++)
        #pragma unroll
        for (int j=0;j<8;j++) acc[i][j] += a[i]*w[j];
    }
    __syncthreads();
  }
  #pragma unroll
  for (int i=0;i<4;i++){
    int row = m_base + rg*4 + i;
    int bm = (row >> 8) % 6;
    #pragma unroll
    for (int j=0;j<8;j++){
      float v = acc[i][j] + bias2d[bm*256 + cg*8 + j];
      if (C)   C[(size_t)row*256 + cg*8 + j] = v;
      if (Cbf) Cbf[(size_t)row*256 + cg*8 + j] = f2bf(v);
    }
  }
}

// ---------------- phase: attention ctx + fc(prev step) + token embed ----------------
__device__ __forceinline__ void attn_phase(SharedU* shp, int b, int step,
    const u16* __restrict__ hR, const u16* __restrict__ eo, u16* __restrict__ cat,
    const int* __restrict__ tf, float* __restrict__ attn_out,
    const int* __restrict__ target, float* __restrict__ outp,
    const float* __restrict__ dec_emb, const u16* __restrict__ top,
    const float* __restrict__ fc_W, const float* __restrict__ fc_b){
  auto& sf = shp->fc;
  int tid = threadIdx.x;
  if (step > 0){
    sf.s[tid]       = ldbfv(&top[(size_t)b*512 + tid]);
    sf.s[tid + 256] = ldbfv(&top[(size_t)b*512 + 256 + tid]);
    __syncthreads();
    if (tid < 3*VDEC){
      int v = tid/3, part = tid - 3*(tid/3);
      int k0 = part*171, k1 = (part==2) ? 512 : (k0+171);
      const float* wr = fc_W + (size_t)v*512;
      float a = 0.f;
      for (int k = k0; k < k1; k++) a += sf.s[k]*wr[k];
      sf.p3[v][part] = a;
    }
    __syncthreads();
    if (tid < VDEC){
      float a = fc_b[tid] + sf.p3[tid][0] + sf.p3[tid][1] + sf.p3[tid][2];
      outp[((size_t)step*BB + b)*VDEC + tid] = a;
      sf.lg[tid] = a;
    }
    __syncthreads();
  }
  int tok;
  if (tf[0]) tok = target[b*TOUT + step];
  else if (step == 0) tok = 1;
  else {
    if (tid == 0){
      int bi = 0; float bv = sf.lg[0];
      for (int v = 1; v < VDEC; v++){ float x = sf.lg[v]; if (x > bv){ bv = x; bi = v; } }
      sf.tok = bi;
    }
    __syncthreads();
    tok = sf.tok;
  }
  cat[(size_t)b*512 + tid] = f2bf(dec_emb[(size_t)tok*EDIM + tid]);
  int hc = tid;
  bool wa = (tf[0] == 0);
  float acc = 0.f;
  for (int d = 0; d < DD; d++){
    float hv = ldbfv(&hR[(size_t)d*BH + (size_t)b*256 + hc]);
    const u16* ep = eo + (size_t)d*BH + (size_t)b*256 + hc;   // eo constant post-bridge: L1-cached OK
    float se = 0.f, ac = 0.f;
    #pragma unroll 8
    for (int t = 0; t < TIN; t++){
      float ev = bf2f(ep[(size_t)t*(DD*BH)]);
      float e = __expf(hv*ev);
      se += e; ac += e*ev;
    }
    acc += ac/se;
    if (wa){
      float inv = 1.f/se;
      for (int t = 0; t < TIN; t++){
        float ev = bf2f(ep[(size_t)t*(DD*BH)]);
        atomicAdd(&attn_out[(((size_t)(step+1)*TIN + t)*DD + d)*BB + b], __expf(hv*ev)*inv);
      }
    }
  }
  cat[(size_t)b*512 + 256 + hc] = f2bf(acc*(1.0f/6.0f));
}

__device__ __forceinline__ void fc_final_phase(SharedU* shp, int b,
    const u16* __restrict__ top, const float* __restrict__ fc_W,
    const float* __restrict__ fc_b, float* __restrict__ outp){
  auto& sf = shp->fc;
  int tid = threadIdx.x;
  sf.s[tid]       = ldbfv(&top[(size_t)b*512 + tid]);
  sf.s[tid + 256] = ldbfv(&top[(size_t)b*512 + 256 + tid]);
  __syncthreads();
  if (tid < 3*VDEC){
    int v = tid/3, part = tid - 3*(tid/3);
    int k0 = part*171, k1 = (part==2) ? 512 : (k0+171);
    const float* wr = fc_W + (size_t)v*512;
    float a = 0.f;
    for (int k = k0; k < k1; k++) a += sf.s[k]*wr[k];
    sf.p3[v][part] = a;
  }
  __syncthreads();
  if (tid < VDEC){
    float a = fc_b[tid] + sf.p3[tid][0] + sf.p3[tid][1] + sf.p3[tid][2];
    outp[((size_t)(TOUT-1)*BB + b)*VDEC + tid] = a;
  }
}

// ---------------- THE megakernel ----------------
// barblk layout (u32, zeroed): [0..255] arr, [320] gen, [336..343] xcd ordinal ctrs, [352] badflag
__global__ __launch_bounds__(256, 1) void mega_kernel(
    const int* __restrict__ target, const int* __restrict__ tf,
    const float* __restrict__ dec_emb, const u16* __restrict__ x_emb,
    const u16* __restrict__ wp_e0, const u16* __restrict__ wp_e1, const u16* __restrict__ wp_e2,
    const u16* __restrict__ wp_d0f, const u16* __restrict__ wp_d1, const u16* __restrict__ wp_d2,
    const float* __restrict__ enc_b, const float* __restrict__ dec_b, const float* __restrict__ fb0,
    const float* __restrict__ lin_h_W1, const float* __restrict__ lin_c_W1, const float* __restrict__ lin_a_W1,
    const float* __restrict__ lin_h_W2, const float* __restrict__ lin_c_W2, const float* __restrict__ lin_a_W2,
    const float* __restrict__ bias2d,
    const float* __restrict__ fc_W, const float* __restrict__ fc_b,
    float* __restrict__ out,
    float* __restrict__ h_all, float* __restrict__ tmp6, float* __restrict__ tmp6c,
    float* __restrict__ dec_c, u16* __restrict__ enc_hA, float* __restrict__ enc_c,
    u16* __restrict__ enc_hB, u16* __restrict__ dec_hA, u16* __restrict__ dec_hB,
    u16* __restrict__ bufA, u16* __restrict__ bufB, u16* __restrict__ cat,
    u16* __restrict__ eo_bf, u32* __restrict__ barblk)
{
  __shared__ SharedU sh;
  __shared__ u32 ord_sh;
  const int bid = blockIdx.x, tid = threadIdx.x;
  u32* arr = barblk;
  u32* gen = barblk + 320;
  u32* ctr = barblk + 336;
  u32* badflag = barblk + 352;
  u32 g = 0;

  // ---- mode detect: claim per-XCD ordinal; verify even 32/XCD distribution ----
  u32 xcc;
  asm volatile("s_getreg_b32 %0, hwreg(HW_REG_XCC_ID)" : "=s"(xcc));
  xcc &= 7u;
  if (tid == 0){
    u32 o = __hip_atomic_fetch_add(&ctr[xcc], 1u, __ATOMIC_RELAXED, __HIP_MEMORY_SCOPE_AGENT);
    ord_sh = o;
    if (o >= 32u)
      __hip_atomic_store(badflag, 1u, __ATOMIC_RELAXED, __HIP_MEMORY_SCOPE_AGENT);
  }
  gridbar(arr, gen, ++g, bid, false);   // slow barrier (full coherence) for mode agreement
  bool fast = (__hip_atomic_load(badflag, __ATOMIC_RELAXED, __HIP_MEMORY_SCOPE_AGENT) == 0u);
  int mt, y;
  if (fast){ mt = (int)xcc; y = (int)ord_sh; }
  else     { mt = bid & 7;  y = bid >> 3;    }

  // -------- encoder: 32 timesteps x 3 stages --------
  for (int t = 0; t < TIN; t++){
    const u16* hRb = (t & 1) ? enc_hB : enc_hA;
    u16*       hWb = (t & 1) ? enc_hA : enc_hB;
    float* hat = h_all + (size_t)t*DD*BH;
    stage_phase<256>(&sh, mt, y, x_emb + (size_t)t*BB*EDIM, wp_e0, enc_b,        hRb, hWb, enc_c, bufA, hat, 0);
    gridbar(arr, gen, ++g, bid, fast);
    stage_phase<512>(&sh, mt, y, bufA,                      wp_e1, enc_b + 2048, hRb, hWb, enc_c, bufB, hat, 1);
    gridbar(arr, gen, ++g, bid, fast);
    stage_phase<512>(&sh, mt, y, bufB,                      wp_e2, enc_b + 4096, hRb, hWb, enc_c, bufA, hat, 2);
    gridbar(arr, gen, ++g, bid, fast);
  }

  // -------- bridges (XCD-local assignments) --------
  mix_phase_local(mt, y, h_all + (size_t)31*DD*BH, tmp6,  lin_h_W2, 1);
  mix_phase_local(mt, y, enc_c,                    tmp6c, lin_c_W2, 1);
  gridbar(arr, gen, ++g, bid, fast);
  if (y < 6)       gemm_tile(&sh, (y*8 + mt)*32,     tmp6,  nullptr, lin_h_W1, bias2d + 1536, dec_hA);
  else if (y < 12) gemm_tile(&sh, ((y-6)*8 + mt)*32, tmp6c, dec_c,   lin_c_W1, bias2d + 3072, nullptr);
  gridbar(arr, gen, ++g, bid, fast);
  mix_phase_local(mt, y, h_all, h_all, lin_a_W2, TIN);
  gridbar(arr, gen, ++g, bid, fast);
  #pragma unroll
  for (int j = 0; j < 6; j++)
    gemm_tile(&sh, ((y + 32*j)*8 + mt)*32, h_all, nullptr, lin_a_W1, bias2d, eo_bf);
  gridbar(arr, gen, ++g, bid, fast);

  // -------- decoder: 28 steps x (attn+fc | stage0 | stage1 | stage2) --------
  float* attn_out = out + (size_t)TOUT*BB*VDEC;
  int b = mt*32 + y;
  for (int i = 0; i < TOUT-1; i++){
    const u16* hRb = (i & 1) ? dec_hB : dec_hA;
    u16*       hWb = (i & 1) ? dec_hA : dec_hB;
    attn_phase(&sh, b, i, hRb, eo_bf, cat, tf, attn_out, target, out, dec_emb, bufA, fc_W, fc_b);
    gridbar(arr, gen, ++g, bid, fast);
    stage_phase<512>(&sh, mt, y, cat,  wp_d0f, fb0,          hRb, hWb, dec_c, bufA, nullptr, 0);
    gridbar(arr, gen, ++g, bid, fast);
    stage_phase<512>(&sh, mt, y, bufA, wp_d1,  dec_b + 2048, hRb, hWb, dec_c, bufB, nullptr, 1);
    gridbar(arr, gen, ++g, bid, fast);
    stage_phase<512>(&sh, mt, y, bufB, wp_d2,  dec_b + 4096, hRb, hWb, dec_c, bufA, nullptr, 2);
    gridbar(arr, gen, ++g, bid, fast);
  }
  fc_final_phase(&sh, b, bufA, fc_W, fc_b, out);
}

// =====================================================================

extern "C" void kernel_launch(void* const* d_in, const int* in_sizes, int n_in,
                              void* d_out, int out_size, void* d_ws, size_t ws_size,
                              hipStream_t stream){
  (void)in_sizes; (void)n_in; (void)out_size; (void)ws_size;
  const int*   input    = (const int*)d_in[0];
  const int*   target   = (const int*)d_in[1];
  const int*   tf       = (const int*)d_in[2];
  const float* enc_emb  = (const float*)d_in[3];
  const float* dec_emb  = (const float*)d_in[4];
  const float* enc_Wih0 = (const float*)d_in[5];
  const float* enc_Wih1 = (const float*)d_in[6];
  const float* enc_Whh  = (const float*)d_in[7];
  const float* enc_b    = (const float*)d_in[8];
  const float* dec_Wih0 = (const float*)d_in[9];
  const float* dec_Wih1 = (const float*)d_in[10];
  const float* dec_Whh  = (const float*)d_in[11];
  const float* dec_b    = (const float*)d_in[12];
  const float* lin_h_W1 = (const float*)d_in[13];
  const float* lin_h_b1 = (const float*)d_in[14];
  const float* lin_h_W2 = (const float*)d_in[15];
  const float* lin_h_b2 = (const float*)d_in[16];
  const float* lin_c_W1 = (const float*)d_in[17];
  const float* lin_c_b1 = (const float*)d_in[18];
  const float* lin_c_W2 = (const float*)d_in[19];
  const float* lin_c_b2 = (const float*)d_in[20];
  const float* lin_a_W1 = (const float*)d_in[21];
  const float* lin_a_b1 = (const float*)d_in[22];
  const float* lin_a_W2 = (const float*)d_in[23];
  const float* lin_a_b2 = (const float*)d_in[24];
  const float* attn_W   = (const float*)d_in[25];
  const float* attn_b   = (const float*)d_in[26];
  const float* fc_W     = (const float*)d_in[27];
  const float* fc_b     = (const float*)d_in[28];
  float* out = (float*)d_out;

  char* base = (char*)d_ws;
  size_t off = 0;
  auto alloc = [&](size_t bytes)->char*{
    char* p = base + off; off += (bytes + 255) & ~(size_t)255; return p;
  };
  float* h_all  = (float*)alloc(sizeof(float)*(size_t)TIN*DD*BH);
  float* tmp6   = (float*)alloc(sizeof(float)*(size_t)DD*BH);
  float* tmp6c  = (float*)alloc(sizeof(float)*(size_t)DD*BH);
  float* dec_c  = (float*)alloc(sizeof(float)*(size_t)DD*BH);
  float* bias2d = (float*)alloc(sizeof(float)*3*6*256);
  // zero block: enc_hA (bf16) + enc_c (fp32), contiguous
  u16*   enc_hA = (u16*)alloc(sizeof(u16)*(size_t)DD*BH + sizeof(float)*(size_t)DD*BH);
  float* enc_c  = (float*)(enc_hA + (size_t)DD*BH);
  u16* enc_hB = (u16*)alloc(sizeof(u16)*(size_t)DD*BH);
  u16* dec_hA = (u16*)alloc(sizeof(u16)*(size_t)DD*BH);
  u16* dec_hB = (u16*)alloc(sizeof(u16)*(size_t)DD*BH);
  u16* x_emb  = (u16*)alloc(sizeof(u16)*(size_t)TIN*BB*EDIM);
  u16* bufA   = (u16*)alloc(sizeof(u16)*(size_t)BB*512);
  u16* bufB   = (u16*)alloc(sizeof(u16)*(size_t)BB*512);
  u16* cat    = (u16*)alloc(sizeof(u16)*(size_t)BB*512);       // [emb | ctx]
  u16* eo_bf  = (u16*)alloc(sizeof(u16)*(size_t)TIN*DD*BH);    // bf16 encoder_outputs
  u16* wp_e0  = (u16*)alloc(sizeof(u16)*(size_t)2048*512);
  u16* wp_e1  = (u16*)alloc(sizeof(u16)*(size_t)2048*768);
  u16* wp_e2  = (u16*)alloc(sizeof(u16)*(size_t)2048*768);
  u16* wp_d0f = (u16*)alloc(sizeof(u16)*(size_t)2048*768);     // fused attn_W . Wih0 | Whh
  u16* wp_d1  = (u16*)alloc(sizeof(u16)*(size_t)2048*768);
  u16* wp_d2  = (u16*)alloc(sizeof(u16)*(size_t)2048*768);
  float* fb0  = (float*)alloc(sizeof(float)*2048);             // fused stage-0 bias
  u32* barblk = (u32*)alloc(sizeof(u32)*512);                  // barrier state (zeroed)

  const int outn = TOUT*BB*VDEC + TOUT*TIN*DD*BB;
  init_out_kernel<<<(outn+255)/256, 256, 0, stream>>>(out, outn);
  fill_zero_u32<<<(DD*BH*6/4 + 255)/256, 256, 0, stream>>>((u32*)enc_hA, DD*BH*6/4);
  fill_zero_u32<<<2, 256, 0, stream>>>(barblk, 512);
  bias2d_kernel<<<1, 256, 0, stream>>>(lin_a_W2, lin_a_b1, lin_a_b2,
                                       lin_h_W2, lin_h_b1, lin_h_b2,
                                       lin_c_W2, lin_c_b1, lin_c_b2, bias2d);
  embed_enc_kernel<<<(TIN*BB*EDIM)/256, 256, 0, stream>>>(input, enc_emb, x_emb);
  pack_w_kernel<<<dim3(2,2048), 256, 0, stream>>>(enc_Wih0, enc_Whh,                       wp_e0, 256, 512);
  pack_w_kernel<<<dim3(3,2048), 256, 0, stream>>>(enc_Wih1, enc_Whh + 2*1024*256,          wp_e1, 512, 768);
  pack_w_kernel<<<dim3(3,2048), 256, 0, stream>>>(enc_Wih1 + (size_t)2*1024*512, enc_Whh + 4*1024*256, wp_e2, 512, 768);
  pack_wfused_kernel<<<dim3(3,2048), 256, 0, stream>>>(dec_Wih0, attn_W, dec_Whh,          wp_d0f);
  biasfold_kernel<<<8, 256, 0, stream>>>(dec_Wih0, attn_b, dec_b, fb0);
  pack_w_kernel<<<dim3(3,2048), 256, 0, stream>>>(dec_Wih1, dec_Whh + 2*1024*256,          wp_d1, 512, 768);
  pack_w_kernel<<<dim3(3,2048), 256, 0, stream>>>(dec_Wih1 + (size_t)2*1024*512, dec_Whh + 4*1024*256, wp_d2, 512, 768);

  mega_kernel<<<NBLK, 256, 0, stream>>>(
      target, tf, dec_emb, x_emb,
      wp_e0, wp_e1, wp_e2, wp_d0f, wp_d1, wp_d2,
      enc_b, dec_b, fb0,
      lin_h_W1, lin_c_W1, lin_a_W1, lin_h_W2, lin_c_W2, lin_a_W2,
      bias2d, fc_W, fc_b, out,
      h_all, tmp6, tmp6c, dec_c, enc_hA, enc_c, enc_hB, dec_hA, dec_hB,
      bufA, bufB, cat, eo_bf, barblk);
}

// Round 5
// 3908.837 us; speedup vs baseline: 2.2896x; 1.1585x over previous
//
#include <hip/hip_runtime.h>
#include <math.h>

#define BB 256
#define TIN 32
#define TOUT 29
#define VDEC 72
#define EDIM 256
#define HDIM 256
#define DD 6
#define BH (BB*HDIM)
#define NBLK 256

typedef unsigned short u16;
typedef unsigned int u32;
typedef __bf16 bf16x8 __attribute__((ext_vector_type(8)));
typedef float f32x4 __attribute__((ext_vector_type(4)));
typedef u16 u16x8 __attribute__((ext_vector_type(8)));

__device__ __forceinline__ float sigmf(float x){ return 1.0f/(1.0f+__expf(-x)); }
__device__ __forceinline__ float tanhf_fast(float x){ return 1.0f - 2.0f/(1.0f+__expf(2.0f*x)); }
__device__ __forceinline__ u16 f2bf(float f){
  u32 u = __builtin_bit_cast(u32, f);
  u32 r = (u + 0x7fffu + ((u>>16)&1u)) >> 16;   // RNE; inputs finite
  return (u16)r;
}
__device__ __forceinline__ float bf2f(u16 s){
  u32 u = ((u32)s)<<16; return __builtin_bit_cast(float, u);
}
__device__ __forceinline__ bf16x8 ldbf8(const u16* p){
  u16x8 t = *(const u16x8*)p; return __builtin_bit_cast(bf16x8, t);
}
// volatile = sc0 = L1-bypass: required for cross-block recurrent data
__device__ __forceinline__ bf16x8 ldbf8v(const u16* p){
  u16x8 t = *(const volatile u16x8*)p; return __builtin_bit_cast(bf16x8, t);
}
__device__ __forceinline__ float ldbfv(const u16* p){ return bf2f(*(const volatile u16*)p); }
__device__ __forceinline__ float ldfv(const float* p){ return *(const volatile float*)p; }
__device__ __forceinline__ f32x4 mfma16(bf16x8 a, bf16x8 b, f32x4 c){
  return __builtin_amdgcn_mfma_f32_16x16x32_bf16(a, b, c, 0, 0, 0);
}

// ---------------- shared memory union (~76 KB) ----------------
struct GmS { float As[32][33]; float Ws[256][34]; };
union SharedU {
  struct { float Gt[2][4][32][18]; } st;          // [khalf][gate][batch][h] partial sums
  GmS gm2[2];                                      // two independent gemm tiles
  struct { float s[512]; float p4[VDEC][4]; float lg[VDEC]; float ctxp[2][256]; int tok; } fc;
};

// ---------------- grid barrier ----------------
__device__ __forceinline__ void gridbar(u32* arr, u32* gen, u32 g, int bid, bool fast){
  __syncthreads();
  if (fast){
    if (threadIdx.x == 0)
      __hip_atomic_store(&arr[bid], g, __ATOMIC_RELAXED, __HIP_MEMORY_SCOPE_AGENT);
    if (bid == 0){
      if (threadIdx.x < 256)
        while (__hip_atomic_load(&arr[threadIdx.x], __ATOMIC_RELAXED, __HIP_MEMORY_SCOPE_AGENT) < g)
          __builtin_amdgcn_s_sleep(1);
      __syncthreads();
      if (threadIdx.x == 0)
        __hip_atomic_store(gen, g, __ATOMIC_RELAXED, __HIP_MEMORY_SCOPE_AGENT);
    } else if (threadIdx.x == 0){
      while (__hip_atomic_load(gen, __ATOMIC_RELAXED, __HIP_MEMORY_SCOPE_AGENT) < g)
        __builtin_amdgcn_s_sleep(1);
    }
  } else {
    if (threadIdx.x == 0)
      __hip_atomic_store(&arr[bid], g, __ATOMIC_RELEASE, __HIP_MEMORY_SCOPE_AGENT);
    if (bid == 0){
      if (threadIdx.x < 256)
        while (__hip_atomic_load(&arr[threadIdx.x], __ATOMIC_RELAXED, __HIP_MEMORY_SCOPE_AGENT) < g)
          __builtin_amdgcn_s_sleep(1);
      __syncthreads();
      if (threadIdx.x == 0)
        __hip_atomic_store(gen, g, __ATOMIC_RELEASE, __HIP_MEMORY_SCOPE_AGENT);
    } else if (threadIdx.x == 0){
      while (__hip_atomic_load(gen, __ATOMIC_RELAXED, __HIP_MEMORY_SCOPE_AGENT) < g)
        __builtin_amdgcn_s_sleep(1);
    }
    __builtin_amdgcn_fence(__ATOMIC_ACQUIRE, "agent");
  }
  __syncthreads();
}

// ---------------- setup kernels ----------------
__global__ void fill_zero_u32(u32* __restrict__ p, int n){
  int i = blockIdx.x*256 + threadIdx.x;
  if (i < n) p[i] = 0u;
}

__global__ void init_out_kernel(float* __restrict__ out, int n){
  int i = blockIdx.x*256 + threadIdx.x;
  if (i >= n) return;
  float v = 0.0f;
  if (i < BB*VDEC && (i % VDEC) == 1) v = 1.0f;   // pred0 one-hot
  out[i] = v;
}

__global__ void bias2d_kernel(const float* __restrict__ W2a, const float* __restrict__ b1a, const float* __restrict__ b2a,
                              const float* __restrict__ W2h, const float* __restrict__ b1h, const float* __restrict__ b2h,
                              const float* __restrict__ W2c, const float* __restrict__ b1c, const float* __restrict__ b2c,
                              float* __restrict__ outp){
  int g = threadIdx.x;
  const float* W2[3] = {W2a, W2h, W2c};
  const float* b1[3] = {b1a, b1h, b1c};
  const float* b2[3] = {b2a, b2h, b2c};
  for (int p = 0; p < 3; p++)
    for (int m = 0; m < 6; m++){
      float s = 0.f;
      for (int l = 0; l < 6; l++) s += W2[p][m*6+l];
      outp[p*1536 + m*256 + g] = s * b1[p][g] + b2[p][m];
    }
}

__global__ void embed_enc_kernel(const int* __restrict__ input, const float* __restrict__ enc_emb,
                                 u16* __restrict__ x_emb){
  int i = blockIdx.x*256 + threadIdx.x;
  int e = i & 255, b = (i >> 8) & 255, t = i >> 16;
  x_emb[i] = f2bf(enc_emb[(size_t)input[b*TIN + t]*EDIM + e]);
}

__global__ void pack_w_kernel(const float* __restrict__ Wih, const float* __restrict__ Whh,
                              u16* __restrict__ dst, int K1, int K){
  int k = blockIdx.x*256 + threadIdx.x;
  int row = blockIdx.y;
  int d = row >> 10, rr = row & 1023;
  int ht = rr >> 6, r = rr & 63;
  int g = (r>>4)*256 + ht*16 + (r&15);
  float v;
  if (k < K1) v = Wih[((size_t)d*1024 + g)*K1 + k];
  else        v = Whh[((size_t)d*1024 + g)*256 + (k - K1)];
  dst[(size_t)row*K + k] = f2bf(v);
}

__global__ void pack_wfused_kernel(const float* __restrict__ Wih0, const float* __restrict__ attn_W,
                                   const float* __restrict__ Whh, u16* __restrict__ dst){
  int k = blockIdx.x*256 + threadIdx.x;
  int row = blockIdx.y;
  int d = row >> 10, rr = row & 1023;
  int ht = rr >> 6, r = rr & 63;
  int g = (r>>4)*256 + ht*16 + (r&15);
  float v;
  if (k >= 512) v = Whh[((size_t)d*1024 + g)*256 + (k - 512)];
  else {
    const float* wr = Wih0 + ((size_t)d*1024 + g)*256;
    float s = 0.f;
    #pragma unroll 4
    for (int o = 0; o < 256; o++) s += wr[o] * attn_W[(size_t)o*512 + k];
    v = s;
  }
  dst[(size_t)row*768 + k] = f2bf(v);
}

__global__ void biasfold_kernel(const float* __restrict__ Wih0, const float* __restrict__ attn_b,
                                const float* __restrict__ dec_b, float* __restrict__ outb){
  int i = blockIdx.x*256 + threadIdx.x;
  int d = i >> 10, g = i & 1023;
  const float* wr = Wih0 + ((size_t)d*1024 + g)*256;
  float s = dec_b[d*1024 + g];
  #pragma unroll 4
  for (int o = 0; o < 256; o++) s += wr[o]*attn_b[o];
  outb[i] = s;
}

// ---------------- phase: fused LSTM stage, 8 waves, K split across wave pairs ----------------
// waves 0-3: gates q, K-half 0;  waves 4-7: gates q, K-half 1. Partials summed via LDS.
template<int K1>
__device__ __forceinline__ void stage_phase(SharedU* shp, int mt, int y,
    const u16* __restrict__ inp, const u16* __restrict__ Wpk, const float* __restrict__ bias_l,
    const u16* __restrict__ hR, u16* __restrict__ hW, float* __restrict__ cBuf,
    u16* __restrict__ inp_out, float* __restrict__ h_all_t, int l){
  auto& ss = shp->st;
  constexpr int K = K1 + 256;
  constexpr int HK = K/2;
  int tid = threadIdx.x;
  int m_base = mt*32;
  int d = y >> 4, ht = y & 15;
  int idx = 2*l + d;
  int q8 = tid >> 6, lane = tid & 63;
  int qg = q8 & 3, kh2 = q8 >> 2;
  int r = lane & 15, lq = lane >> 4;
  const u16* a0p = inp + (size_t)(m_base + r)*K1 + lq*8;
  const u16* a1p = a0p + (size_t)16*K1;
  const u16* h0p = hR + (size_t)idx*BH + (size_t)(m_base + r)*HDIM + lq*8;
  const u16* h1p = h0p + 16*HDIM;
  const u16* wp  = Wpk + (size_t)((d*16+ht)*64 + qg*16 + r)*K + lq*8;
  const int cbase = kh2*HK;
  f32x4 acc0 = {0.f,0.f,0.f,0.f}, acc1 = {0.f,0.f,0.f,0.f};
  #pragma unroll
  for (int c = 0; c < HK; c += 32){
    int col = cbase + c;
    bool ina = (col < K1);
    const u16* pa0 = ina ? (a0p + col) : (h0p + (col - K1));
    const u16* pa1 = ina ? (a1p + col) : (h1p + (col - K1));
    bf16x8 a0 = ldbf8v(pa0);
    bf16x8 a1 = ldbf8v(pa1);
    bf16x8 bq = ldbf8(wp + col);
    acc0 = mfma16(a0, bq, acc0);
    acc1 = mfma16(a1, bq, acc1);
  }
  #pragma unroll
  for (int rr = 0; rr < 4; rr++){
    ss.Gt[kh2][qg][lq*4 + rr][r]      = acc0[rr];
    ss.Gt[kh2][qg][16 + lq*4 + rr][r] = acc1[rr];
  }
  __syncthreads();
  const float* bias = bias_l + d*1024;
  {
    int bb = tid >> 4, h2 = tid & 15;          // 512 threads -> one (b,h) each
    int b = m_base + bb, h = ht*16 + h2;
    float iv = ss.Gt[0][0][bb][h2] + ss.Gt[1][0][bb][h2] + bias[h];
    float fv = ss.Gt[0][1][bb][h2] + ss.Gt[1][1][bb][h2] + bias[256 + h];
    float gv = ss.Gt[0][2][bb][h2] + ss.Gt[1][2][bb][h2] + bias[512 + h];
    float ov = ss.Gt[0][3][bb][h2] + ss.Gt[1][3][bb][h2] + bias[768 + h];
    size_t off = (size_t)idx*BH + (size_t)b*HDIM + h;
    float cold = cBuf[off];                    // own slice all kernel long: L1-coherent
    float cc = sigmf(fv)*cold + sigmf(iv)*tanhf_fast(gv);
    float hv = sigmf(ov)*tanhf_fast(cc);
    cBuf[off] = cc;
    u16 hb = f2bf(hv);
    hW[off] = hb;
    inp_out[(size_t)b*512 + d*HDIM + h] = hb;
    if (h_all_t) h_all_t[off] = hv;
  }
}

// ---------------- phase: 6x6 layer-mix for one (b,h) at timestep t ----------------
__device__ __forceinline__ void mix_one(int b, int h, const float* __restrict__ inp,
    float* __restrict__ outp, const float* __restrict__ W2, int t){
  size_t base2 = ((size_t)t*6)*BH + (size_t)b*256 + h;
  float v[6];
  #pragma unroll
  for (int l = 0; l < 6; l++) v[l] = ldfv(&inp[base2 + (size_t)l*BH]);
  #pragma unroll
  for (int m = 0; m < 6; m++){
    float s = 0.f;
    #pragma unroll
    for (int l = 0; l < 6; l++) s += W2[m*6+l]*v[l];
    outp[base2 + (size_t)m*BH] = s;
  }
}

// ---------------- phase: fp32 gemm tile (256 threads per call; conflict-free Ws reads) ----------------
__device__ __forceinline__ void gemm_tile(GmS& sg, int tid, int m_base,
    const float* __restrict__ A, float* __restrict__ C, const float* __restrict__ W,
    const float* __restrict__ bias2d, u16* __restrict__ Cbf){
  int rg = tid >> 5, cg = tid & 31;
  float acc[4][8];
  #pragma unroll
  for (int i=0;i<4;i++)
    #pragma unroll
    for (int j=0;j<8;j++) acc[i][j]=0.f;
  for (int k0 = 0; k0 < 256; k0 += 32){
    #pragma unroll
    for (int p=0;p<4;p++) sg.As[rg + p*8][cg] = ldfv(&A[(size_t)(m_base + rg + p*8)*256 + k0 + cg]);
    #pragma unroll
    for (int p=0;p<32;p++) sg.Ws[rg + p*8][cg] = W[(size_t)(rg + p*8)*256 + k0 + cg];
    __syncthreads();
    #pragma unroll
    for (int kk=0; kk<32; kk++){
      float a[4], w[8];
      #pragma unroll
      for (int i=0;i<4;i++) a[i] = sg.As[rg*4+i][kk];
      #pragma unroll
      for (int j=0;j<8;j++) w[j] = sg.Ws[cg + 32*j][kk];   // stride-34 -> 2-way, free
      #pragma unroll
      for (int i=0;i<4;i++)
        #pragma unroll
        for (int j=0;j<8;j++) acc[i][j] += a[i]*w[j];
    }
    __syncthreads();
  }
  #pragma unroll
  for (int i=0;i<4;i++){
    int row = m_base + rg*4 + i;
    int bm = (row >> 8) % 6;
    #pragma unroll
    for (int j=0;j<8;j++){
      int col = cg + 32*j;
      float v = acc[i][j] + bias2d[bm*256 + col];
      if (C)   C[(size_t)row*256 + col] = v;
      if (Cbf) Cbf[(size_t)row*256 + col] = f2bf(v);
    }
  }
}

// ---------------- phase: attention ctx + fc(prev step) + token embed (512 thr) ----------------
__device__ __forceinline__ void attn_phase(SharedU* shp, int b, int step,
    const u16* __restrict__ hR, const u16* __restrict__ eo, u16* __restrict__ cat,
    const int* __restrict__ tf, float* __restrict__ attn_out,
    const int* __restrict__ target, float* __restrict__ outp,
    const float* __restrict__ dec_emb, const u16* __restrict__ top,
    const float* __restrict__ fc_W, const float* __restrict__ fc_b){
  auto& sf = shp->fc;
  int tid = threadIdx.x;
  if (step > 0){
    sf.s[tid] = ldbfv(&top[(size_t)b*512 + tid]);
    __syncthreads();
    if (tid < 4*VDEC){
      int v = tid >> 2, part = tid & 3;
      int k0 = part*128;
      const float* wr = fc_W + (size_t)v*512;
      float a = 0.f;
      #pragma unroll 4
      for (int k = k0; k < k0+128; k++) a += sf.s[k]*wr[k];
      sf.p4[v][part] = a;
    }
    __syncthreads();
    if (tid < VDEC){
      float a = fc_b[tid] + sf.p4[tid][0] + sf.p4[tid][1] + sf.p4[tid][2] + sf.p4[tid][3];
      outp[((size_t)step*BB + b)*VDEC + tid] = a;
      sf.lg[tid] = a;
    }
    __syncthreads();
  }
  int tok;
  if (tf[0]) tok = target[b*TOUT + step];
  else if (step == 0) tok = 1;
  else {
    if (tid == 0){
      int bi = 0; float bv = sf.lg[0];
      for (int v = 1; v < VDEC; v++){ float x = sf.lg[v]; if (x > bv){ bv = x; bi = v; } }
      sf.tok = bi;
    }
    __syncthreads();
    tok = sf.tok;
  }
  if (tid < 256) cat[(size_t)b*512 + tid] = f2bf(dec_emb[(size_t)tok*EDIM + tid]);
  // ctx: d split across thread halves
  int hc = tid & 255, dhalf = tid >> 8;
  bool wa = (tf[0] == 0);
  float acc = 0.f;
  for (int dd = 0; dd < 3; dd++){
    int d = dhalf*3 + dd;
    float hv = ldbfv(&hR[(size_t)d*BH + (size_t)b*256 + hc]);
    const u16* ep = eo + (size_t)d*BH + (size_t)b*256 + hc;
    float se = 0.f, ac = 0.f;
    #pragma unroll 8
    for (int t = 0; t < TIN; t++){
      float ev = bf2f(ep[(size_t)t*(DD*BH)]);
      float e = __expf(hv*ev);
      se += e; ac += e*ev;
    }
    acc += ac/se;
    if (wa){
      float inv = 1.f/se;
      for (int t = 0; t < TIN; t++){
        float ev = bf2f(ep[(size_t)t*(DD*BH)]);
        atomicAdd(&attn_out[(((size_t)(step+1)*TIN + t)*DD + d)*BB + b], __expf(hv*ev)*inv);
      }
    }
  }
  sf.ctxp[dhalf][hc] = acc;
  __syncthreads();
  if (tid < 256)
    cat[(size_t)b*512 + 256 + tid] = f2bf((sf.ctxp[0][tid] + sf.ctxp[1][tid])*(1.0f/6.0f));
}

__device__ __forceinline__ void fc_final_phase(SharedU* shp, int b,
    const u16* __restrict__ top, const float* __restrict__ fc_W,
    const float* __restrict__ fc_b, float* __restrict__ outp){
  auto& sf = shp->fc;
  int tid = threadIdx.x;
  sf.s[tid] = ldbfv(&top[(size_t)b*512 + tid]);
  __syncthreads();
  if (tid < 4*VDEC){
    int v = tid >> 2, part = tid & 3;
    int k0 = part*128;
    const float* wr = fc_W + (size_t)v*512;
    float a = 0.f;
    #pragma unroll 4
    for (int k = k0; k < k0+128; k++) a += sf.s[k]*wr[k];
    sf.p4[v][part] = a;
  }
  __syncthreads();
  if (tid < VDEC){
    float a = fc_b[tid] + sf.p4[tid][0] + sf.p4[tid][1] + sf.p4[tid][2] + sf.p4[tid][3];
    outp[((size_t)(TOUT-1)*BB + b)*VDEC + tid] = a;
  }
}

// ---------------- THE megakernel (512 threads = 8 waves = 2 waves/SIMD) ----------------
__global__ __launch_bounds__(512, 2) void mega_kernel(
    const int* __restrict__ target, const int* __restrict__ tf,
    const float* __restrict__ dec_emb, const u16* __restrict__ x_emb,
    const u16* __restrict__ wp_e0, const u16* __restrict__ wp_e1, const u16* __restrict__ wp_e2,
    const u16* __restrict__ wp_d0f, const u16* __restrict__ wp_d1, const u16* __restrict__ wp_d2,
    const float* __restrict__ enc_b, const float* __restrict__ dec_b, const float* __restrict__ fb0,
    const float* __restrict__ lin_h_W1, const float* __restrict__ lin_c_W1, const float* __restrict__ lin_a_W1,
    const float* __restrict__ lin_h_W2, const float* __restrict__ lin_c_W2, const float* __restrict__ lin_a_W2,
    const float* __restrict__ bias2d,
    const float* __restrict__ fc_W, const float* __restrict__ fc_b,
    float* __restrict__ out,
    float* __restrict__ h_all, float* __restrict__ tmp6, float* __restrict__ tmp6c,
    float* __restrict__ dec_c, u16* __restrict__ enc_hA, float* __restrict__ enc_c,
    u16* __restrict__ enc_hB, u16* __restrict__ dec_hA, u16* __restrict__ dec_hB,
    u16* __restrict__ bufA, u16* __restrict__ bufB, u16* __restrict__ cat,
    u16* __restrict__ eo_bf, u32* __restrict__ barblk)
{
  __shared__ SharedU sh;
  __shared__ u32 ord_sh;
  const int bid = blockIdx.x, tid = threadIdx.x;
  u32* arr = barblk;
  u32* gen = barblk + 320;
  u32* ctr = barblk + 336;
  u32* badflag = barblk + 352;
  u32 g = 0;

  // ---- mode detect ----
  u32 xcc;
  asm volatile("s_getreg_b32 %0, hwreg(HW_REG_XCC_ID)" : "=s"(xcc));
  xcc &= 7u;
  if (tid == 0){
    u32 o = __hip_atomic_fetch_add(&ctr[xcc], 1u, __ATOMIC_RELAXED, __HIP_MEMORY_SCOPE_AGENT);
    ord_sh = o;
    if (o >= 32u)
      __hip_atomic_store(badflag, 1u, __ATOMIC_RELAXED, __HIP_MEMORY_SCOPE_AGENT);
  }
  gridbar(arr, gen, ++g, bid, false);
  bool fast = (__hip_atomic_load(badflag, __ATOMIC_RELAXED, __HIP_MEMORY_SCOPE_AGENT) == 0u);
  int mt, y;
  if (fast){ mt = (int)xcc; y = (int)ord_sh; }
  else     { mt = bid & 7;  y = bid >> 3;    }
  const int half = tid >> 8, htid = tid & 255;

  // -------- encoder: 32 timesteps x 3 stages --------
  for (int t = 0; t < TIN; t++){
    const u16* hRb = (t & 1) ? enc_hB : enc_hA;
    u16*       hWb = (t & 1) ? enc_hA : enc_hB;
    float* hat = h_all + (size_t)t*DD*BH;
    stage_phase<256>(&sh, mt, y, x_emb + (size_t)t*BB*EDIM, wp_e0, enc_b,        hRb, hWb, enc_c, bufA, hat, 0);
    gridbar(arr, gen, ++g, bid, fast);
    stage_phase<512>(&sh, mt, y, bufA,                      wp_e1, enc_b + 2048, hRb, hWb, enc_c, bufB, hat, 1);
    gridbar(arr, gen, ++g, bid, fast);
    stage_phase<512>(&sh, mt, y, bufB,                      wp_e2, enc_b + 4096, hRb, hWb, enc_c, bufA, hat, 2);
    gridbar(arr, gen, ++g, bid, fast);
  }

  // -------- bridges (fused): mixes, then all gemms --------
  {
    int b = mt*32 + y;
    if (half == 0) mix_one(b, htid, h_all + (size_t)31*DD*BH, tmp6,  lin_h_W2, 0);
    else           mix_one(b, htid, enc_c,                    tmp6c, lin_c_W2, 0);
    __syncthreads();                               // a-mix below overwrites h_all[31]
    for (int t2 = half*16; t2 < half*16 + 16; t2++)
      mix_one(b, htid, h_all, h_all, lin_a_W2, t2);
  }
  gridbar(arr, gen, ++g, bid, fast);
  if (y < 6)       gemm_tile(sh.gm2[half], htid, (y*8 + mt)*32,     tmp6,  nullptr, lin_h_W1, bias2d + 1536, dec_hA);
  else if (y < 12) gemm_tile(sh.gm2[half], htid, ((y-6)*8 + mt)*32, tmp6c, dec_c,   lin_c_W1, bias2d + 3072, nullptr);
  #pragma unroll
  for (int jj = 0; jj < 3; jj++){
    int j = half*3 + jj;
    gemm_tile(sh.gm2[half], htid, ((y + 32*j)*8 + mt)*32, h_all, nullptr, lin_a_W1, bias2d, eo_bf);
  }
  gridbar(arr, gen, ++g, bid, fast);

  // -------- decoder: 28 steps x (attn+fc | stage0 | stage1 | stage2) --------
  float* attn_out = out + (size_t)TOUT*BB*VDEC;
  int b = mt*32 + y;
  for (int i = 0; i < TOUT-1; i++){
    const u16* hRb = (i & 1) ? dec_hB : dec_hA;
    u16*       hWb = (i & 1) ? dec_hA : dec_hB;
    attn_phase(&sh, b, i, hRb, eo_bf, cat, tf, attn_out, target, out, dec_emb, bufA, fc_W, fc_b);
    gridbar(arr, gen, ++g, bid, fast);
    stage_phase<512>(&sh, mt, y, cat,  wp_d0f, fb0,          hRb, hWb, dec_c, bufA, nullptr, 0);
    gridbar(arr, gen, ++g, bid, fast);
    stage_phase<512>(&sh, mt, y, bufA, wp_d1,  dec_b + 2048, hRb, hWb, dec_c, bufB, nullptr, 1);
    gridbar(arr, gen, ++g, bid, fast);
    stage_phase<512>(&sh, mt, y, bufB, wp_d2,  dec_b + 4096, hRb, hWb, dec_c, bufA, nullptr, 2);
    gridbar(arr, gen, ++g, bid, fast);
  }
  fc_final_phase(&sh, b, bufA, fc_W, fc_b, out);
}

// =====================================================================

extern "C" void kernel_launch(void* const* d_in, const int* in_sizes, int n_in,
                              void* d_out, int out_size, void* d_ws, size_t ws_size,
                              hipStream_t stream){
  (void)in_sizes; (void)n_in; (void)out_size; (void)ws_size;
  const int*   input    = (const int*)d_in[0];
  const int*   target   = (const int*)d_in[1];
  const int*   tf       = (const int*)d_in[2];
  const float* enc_emb  = (const float*)d_in[3];
  const float* dec_emb  = (const float*)d_in[4];
  const float* enc_Wih0 = (const float*)d_in[5];
  const float* enc_Wih1 = (const float*)d_in[6];
  const float* enc_Whh  = (const float*)d_in[7];
  const float* enc_b    = (const float*)d_in[8];
  const float* dec_Wih0 = (const float*)d_in[9];
  const float* dec_Wih1 = (const float*)d_in[10];
  const float* dec_Whh  = (const float*)d_in[11];
  const float* dec_b    = (const float*)d_in[12];
  const float* lin_h_W1 = (const float*)d_in[13];
  const float* lin_h_b1 = (const float*)d_in[14];
  const float* lin_h_W2 = (const float*)d_in[15];
  const float* lin_h_b2 = (const float*)d_in[16];
  const float* lin_c_W1 = (const float*)d_in[17];
  const float* lin_c_b1 = (const float*)d_in[18];
  const float* lin_c_W2 = (const float*)d_in[19];
  const float* lin_c_b2 = (const float*)d_in[20];
  const float* lin_a_W1 = (const float*)d_in[21];
  const float* lin_a_b1 = (const float*)d_in[22];
  const float* lin_a_W2 = (const float*)d_in[23];
  const float* lin_a_b2 = (const float*)d_in[24];
  const float* attn_W   = (const float*)d_in[25];
  const float* attn_b   = (const float*)d_in[26];
  const float* fc_W     = (const float*)d_in[27];
  const float* fc_b     = (const float*)d_in[28];
  float* out = (float*)d_out;

  char* base = (char*)d_ws;
  size_t off = 0;
  auto alloc = [&](size_t bytes)->char*{
    char* p = base + off; off += (bytes + 255) & ~(size_t)255; return p;
  };
  float* h_all  = (float*)alloc(sizeof(float)*(size_t)TIN*DD*BH);
  float* tmp6   = (float*)alloc(sizeof(float)*(size_t)DD*BH);
  float* tmp6c  = (float*)alloc(sizeof(float)*(size_t)DD*BH);
  float* dec_c  = (float*)alloc(sizeof(float)*(size_t)DD*BH);
  float* bias2d = (float*)alloc(sizeof(float)*3*6*256);
  u16*   enc_hA = (u16*)alloc(sizeof(u16)*(size_t)DD*BH + sizeof(float)*(size_t)DD*BH);
  float* enc_c  = (float*)(enc_hA + (size_t)DD*BH);
  u16* enc_hB = (u16*)alloc(sizeof(u16)*(size_t)DD*BH);
  u16* dec_hA = (u16*)alloc(sizeof(u16)*(size_t)DD*BH);
  u16* dec_hB = (u16*)alloc(sizeof(u16)*(size_t)DD*BH);
  u16* x_emb  = (u16*)alloc(sizeof(u16)*(size_t)TIN*BB*EDIM);
  u16* bufA   = (u16*)alloc(sizeof(u16)*(size_t)BB*512);
  u16* bufB   = (u16*)alloc(sizeof(u16)*(size_t)BB*512);
  u16* cat    = (u16*)alloc(sizeof(u16)*(size_t)BB*512);
  u16* eo_bf  = (u16*)alloc(sizeof(u16)*(size_t)TIN*DD*BH);
  u16* wp_e0  = (u16*)alloc(sizeof(u16)*(size_t)2048*512);
  u16* wp_e1  = (u16*)alloc(sizeof(u16)*(size_t)2048*768);
  u16* wp_e2  = (u16*)alloc(sizeof(u16)*(size_t)2048*768);
  u16* wp_d0f = (u16*)alloc(sizeof(u16)*(size_t)2048*768);
  u16* wp_d1  = (u16*)alloc(sizeof(u16)*(size_t)2048*768);
  u16* wp_d2  = (u16*)alloc(sizeof(u16)*(size_t)2048*768);
  float* fb0  = (float*)alloc(sizeof(float)*2048);
  u32* barblk = (u32*)alloc(sizeof(u32)*512);

  const int outn = TOUT*BB*VDEC + TOUT*TIN*DD*BB;
  init_out_kernel<<<(outn+255)/256, 256, 0, stream>>>(out, outn);
  fill_zero_u32<<<(DD*BH*6/4 + 255)/256, 256, 0, stream>>>((u32*)enc_hA, DD*BH*6/4);
  fill_zero_u32<<<2, 256, 0, stream>>>(barblk, 512);
  bias2d_kernel<<<1, 256, 0, stream>>>(lin_a_W2, lin_a_b1, lin_a_b2,
                                       lin_h_W2, lin_h_b1, lin_h_b2,
                                       lin_c_W2, lin_c_b1, lin_c_b2, bias2d);
  embed_enc_kernel<<<(TIN*BB*EDIM)/256, 256, 0, stream>>>(input, enc_emb, x_emb);
  pack_w_kernel<<<dim3(2,2048), 256, 0, stream>>>(enc_Wih0, enc_Whh,                       wp_e0, 256, 512);
  pack_w_kernel<<<dim3(3,2048), 256, 0, stream>>>(enc_Wih1, enc_Whh + 2*1024*256,          wp_e1, 512, 768);
  pack_w_kernel<<<dim3(3,2048), 256, 0, stream>>>(enc_Wih1 + (size_t)2*1024*512, enc_Whh + 4*1024*256, wp_e2, 512, 768);
  pack_wfused_kernel<<<dim3(3,2048), 256, 0, stream>>>(dec_Wih0, attn_W, dec_Whh,          wp_d0f);
  biasfold_kernel<<<8, 256, 0, stream>>>(dec_Wih0, attn_b, dec_b, fb0);
  pack_w_kernel<<<dim3(3,2048), 256, 0, stream>>>(dec_Wih1, dec_Whh + 2*1024*256,          wp_d1, 512, 768);
  pack_w_kernel<<<dim3(3,2048), 256, 0, stream>>>(dec_Wih1 + (size_t)2*1024*512, dec_Whh + 4*1024*256, wp_d2, 512, 768);

  mega_kernel<<<NBLK, 512, 0, stream>>>(
      target, tf, dec_emb, x_emb,
      wp_e0, wp_e1, wp_e2, wp_d0f, wp_d1, wp_d2,
      enc_b, dec_b, fb0,
      lin_h_W1, lin_c_W1, lin_a_W1, lin_h_W2, lin_c_W2, lin_a_W2,
      bias2d, fc_W, fc_b, out,
      h_all, tmp6, tmp6c, dec_c, enc_hA, enc_c, enc_hB, dec_hA, dec_hB,
      bufA, bufB, cat, eo_bf, barblk);
}

// Round 6
// 3895.882 us; speedup vs baseline: 2.2972x; 1.0033x over previous
//
#include <hip/hip_runtime.h>
#include <math.h>

#define BB 256
#define TIN 32
#define TOUT 29
#define VDEC 72
#define EDIM 256
#define HDIM 256
#define DD 6
#define BH (BB*HDIM)
#define NBLK 256

typedef unsigned short u16;
typedef unsigned int u32;
typedef __bf16 bf16x8 __attribute__((ext_vector_type(8)));
typedef float f32x4 __attribute__((ext_vector_type(4)));
typedef u16 u16x8 __attribute__((ext_vector_type(8)));

__device__ __forceinline__ float sigmf(float x){ return 1.0f/(1.0f+__expf(-x)); }
__device__ __forceinline__ float tanhf_fast(float x){ return 1.0f - 2.0f/(1.0f+__expf(2.0f*x)); }
__device__ __forceinline__ u16 f2bf(float f){
  u32 u = __builtin_bit_cast(u32, f);
  u32 r = (u + 0x7fffu + ((u>>16)&1u)) >> 16;   // RNE; inputs finite
  return (u16)r;
}
__device__ __forceinline__ float bf2f(u16 s){
  u32 u = ((u32)s)<<16; return __builtin_bit_cast(float, u);
}
__device__ __forceinline__ bf16x8 ldbf8(const u16* p){
  u16x8 t = *(const u16x8*)p; return __builtin_bit_cast(bf16x8, t);
}
// volatile = sc0 = L1-bypass: required for cross-block recurrent data
__device__ __forceinline__ bf16x8 ldbf8v(const u16* p){
  u16x8 t = *(const volatile u16x8*)p; return __builtin_bit_cast(bf16x8, t);
}
__device__ __forceinline__ float ldbfv(const u16* p){ return bf2f(*(const volatile u16*)p); }
__device__ __forceinline__ float ldfv(const float* p){ return *(const volatile float*)p; }
__device__ __forceinline__ f32x4 mfma16(bf16x8 a, bf16x8 b, f32x4 c){
  return __builtin_amdgcn_mfma_f32_16x16x32_bf16(a, b, c, 0, 0, 0);
}

// ---------------- shared memory union (~76 KB) ----------------
struct GmS { float As[32][33]; float Ws[256][34]; };
union SharedU {
  struct { float Gt[2][4][32][18]; } st;          // [khalf][gate][batch][h] partial sums
  GmS gm2[2];                                      // two independent gemm tiles
  struct { float s[512]; float p4[VDEC][4]; float lg[VDEC]; float ctxp[2][256]; int tok; } fc;
};

// ---------------- barriers ----------------
// barblk u32 layout: [0..255] slow arr; [320] slow gen; [336..343] xcd ctrs;
// [352] badflag; [384 + mt*32] fast cnt; [384 + mt*32 + 16] fast gen.
// fast: XCD-local 32-block barrier — one fetch_add + one flag, all data is
//       XCD-local (same L2), so NO cache maintenance is needed.
// slow: full agent release/acquire grid barrier — correct for any mapping.
__device__ __forceinline__ void xbar(u32* barblk, int mt, u32 g, int bid, bool fast){
  __syncthreads();
  if (fast){
    u32* cnt  = barblk + 384 + mt*32;
    u32* genx = cnt + 16;
    if (threadIdx.x == 0){
      u32 old = __hip_atomic_fetch_add(cnt, 1u, __ATOMIC_RELAXED, __HIP_MEMORY_SCOPE_AGENT);
      if (old == 31u){
        __hip_atomic_store(cnt, 0u, __ATOMIC_RELAXED, __HIP_MEMORY_SCOPE_AGENT);
        __hip_atomic_store(genx, g, __ATOMIC_RELEASE, __HIP_MEMORY_SCOPE_AGENT);
      } else {
        while (__hip_atomic_load(genx, __ATOMIC_RELAXED, __HIP_MEMORY_SCOPE_AGENT) < g)
          __builtin_amdgcn_s_sleep(2);
      }
    }
    __syncthreads();
  } else {
    u32* arr = barblk;
    u32* gen = barblk + 320;
    if (threadIdx.x == 0)
      __hip_atomic_store(&arr[bid], g, __ATOMIC_RELEASE, __HIP_MEMORY_SCOPE_AGENT);
    if (bid == 0){
      if (threadIdx.x < 256)
        while (__hip_atomic_load(&arr[threadIdx.x], __ATOMIC_RELAXED, __HIP_MEMORY_SCOPE_AGENT) < g)
          __builtin_amdgcn_s_sleep(2);
      __syncthreads();
      if (threadIdx.x == 0)
        __hip_atomic_store(gen, g, __ATOMIC_RELEASE, __HIP_MEMORY_SCOPE_AGENT);
    } else if (threadIdx.x == 0){
      while (__hip_atomic_load(gen, __ATOMIC_RELAXED, __HIP_MEMORY_SCOPE_AGENT) < g)
        __builtin_amdgcn_s_sleep(2);
    }
    __builtin_amdgcn_fence(__ATOMIC_ACQUIRE, "agent");
    __syncthreads();
  }
}

// ---------------- setup kernels ----------------
__global__ void fill_zero_u32(u32* __restrict__ p, int n){
  int i = blockIdx.x*256 + threadIdx.x;
  if (i < n) p[i] = 0u;
}

__global__ void init_out_kernel(float* __restrict__ out, int n){
  int i = blockIdx.x*256 + threadIdx.x;
  if (i >= n) return;
  float v = 0.0f;
  if (i < BB*VDEC && (i % VDEC) == 1) v = 1.0f;   // pred0 one-hot
  out[i] = v;
}

__global__ void bias2d_kernel(const float* __restrict__ W2a, const float* __restrict__ b1a, const float* __restrict__ b2a,
                              const float* __restrict__ W2h, const float* __restrict__ b1h, const float* __restrict__ b2h,
                              const float* __restrict__ W2c, const float* __restrict__ b1c, const float* __restrict__ b2c,
                              float* __restrict__ outp){
  int g = threadIdx.x;
  const float* W2[3] = {W2a, W2h, W2c};
  const float* b1[3] = {b1a, b1h, b1c};
  const float* b2[3] = {b2a, b2h, b2c};
  for (int p = 0; p < 3; p++)
    for (int m = 0; m < 6; m++){
      float s = 0.f;
      for (int l = 0; l < 6; l++) s += W2[p][m*6+l];
      outp[p*1536 + m*256 + g] = s * b1[p][g] + b2[p][m];
    }
}

__global__ void embed_enc_kernel(const int* __restrict__ input, const float* __restrict__ enc_emb,
                                 u16* __restrict__ x_emb){
  int i = blockIdx.x*256 + threadIdx.x;
  int e = i & 255, b = (i >> 8) & 255, t = i >> 16;
  x_emb[i] = f2bf(enc_emb[(size_t)input[b*TIN + t]*EDIM + e]);
}

__global__ void pack_w_kernel(const float* __restrict__ Wih, const float* __restrict__ Whh,
                              u16* __restrict__ dst, int K1, int K){
  int k = blockIdx.x*256 + threadIdx.x;
  int row = blockIdx.y;
  int d = row >> 10, rr = row & 1023;
  int ht = rr >> 6, r = rr & 63;
  int g = (r>>4)*256 + ht*16 + (r&15);
  float v;
  if (k < K1) v = Wih[((size_t)d*1024 + g)*K1 + k];
  else        v = Whh[((size_t)d*1024 + g)*256 + (k - K1)];
  dst[(size_t)row*K + k] = f2bf(v);
}

__global__ void pack_wfused_kernel(const float* __restrict__ Wih0, const float* __restrict__ attn_W,
                                   const float* __restrict__ Whh, u16* __restrict__ dst){
  int k = blockIdx.x*256 + threadIdx.x;
  int row = blockIdx.y;
  int d = row >> 10, rr = row & 1023;
  int ht = rr >> 6, r = rr & 63;
  int g = (r>>4)*256 + ht*16 + (r&15);
  float v;
  if (k >= 512) v = Whh[((size_t)d*1024 + g)*256 + (k - 512)];
  else {
    const float* wr = Wih0 + ((size_t)d*1024 + g)*256;
    float s = 0.f;
    #pragma unroll 4
    for (int o = 0; o < 256; o++) s += wr[o] * attn_W[(size_t)o*512 + k];
    v = s;
  }
  dst[(size_t)row*768 + k] = f2bf(v);
}

__global__ void biasfold_kernel(const float* __restrict__ Wih0, const float* __restrict__ attn_b,
                                const float* __restrict__ dec_b, float* __restrict__ outb){
  int i = blockIdx.x*256 + threadIdx.x;
  int d = i >> 10, g = i & 1023;
  const float* wr = Wih0 + ((size_t)d*1024 + g)*256;
  float s = dec_b[d*1024 + g];
  #pragma unroll 4
  for (int o = 0; o < 256; o++) s += wr[o]*attn_b[o];
  outb[i] = s;
}

// ---------------- phase: fused LSTM stage, 8 waves, K split across wave pairs ----------------
template<int K1>
__device__ __forceinline__ void stage_phase(SharedU* shp, int mt, int y,
    const u16* __restrict__ inp, const u16* __restrict__ Wpk, const float* __restrict__ bias_l,
    const u16* __restrict__ hR, u16* __restrict__ hW, float* __restrict__ cBuf,
    u16* __restrict__ inp_out, float* __restrict__ h_all_t, int l){
  auto& ss = shp->st;
  constexpr int K = K1 + 256;
  constexpr int HK = K/2;
  int tid = threadIdx.x;
  int m_base = mt*32;
  int d = y >> 4, ht = y & 15;
  int idx = 2*l + d;
  int q8 = tid >> 6, lane = tid & 63;
  int qg = q8 & 3, kh2 = q8 >> 2;
  int r = lane & 15, lq = lane >> 4;
  const u16* a0p = inp + (size_t)(m_base + r)*K1 + lq*8;
  const u16* a1p = a0p + (size_t)16*K1;
  const u16* h0p = hR + (size_t)idx*BH + (size_t)(m_base + r)*HDIM + lq*8;
  const u16* h1p = h0p + 16*HDIM;
  const u16* wp  = Wpk + (size_t)((d*16+ht)*64 + qg*16 + r)*K + lq*8;
  const int cbase = kh2*HK;
  f32x4 acc0 = {0.f,0.f,0.f,0.f}, acc1 = {0.f,0.f,0.f,0.f};
  #pragma unroll
  for (int c = 0; c < HK; c += 32){
    int col = cbase + c;
    bool ina = (col < K1);
    const u16* pa0 = ina ? (a0p + col) : (h0p + (col - K1));
    const u16* pa1 = ina ? (a1p + col) : (h1p + (col - K1));
    bf16x8 a0 = ldbf8v(pa0);
    bf16x8 a1 = ldbf8v(pa1);
    bf16x8 bq = ldbf8(wp + col);
    acc0 = mfma16(a0, bq, acc0);
    acc1 = mfma16(a1, bq, acc1);
  }
  __syncthreads();   // Gt may still be read by the previous fused phase in this block
  #pragma unroll
  for (int rr = 0; rr < 4; rr++){
    ss.Gt[kh2][qg][lq*4 + rr][r]      = acc0[rr];
    ss.Gt[kh2][qg][16 + lq*4 + rr][r] = acc1[rr];
  }
  __syncthreads();
  const float* bias = bias_l + d*1024;
  {
    int bb = tid >> 4, h2 = tid & 15;          // 512 threads -> one (b,h) each
    int b = m_base + bb, h = ht*16 + h2;
    float iv = ss.Gt[0][0][bb][h2] + ss.Gt[1][0][bb][h2] + bias[h];
    float fv = ss.Gt[0][1][bb][h2] + ss.Gt[1][1][bb][h2] + bias[256 + h];
    float gv = ss.Gt[0][2][bb][h2] + ss.Gt[1][2][bb][h2] + bias[512 + h];
    float ov = ss.Gt[0][3][bb][h2] + ss.Gt[1][3][bb][h2] + bias[768 + h];
    size_t off = (size_t)idx*BH + (size_t)b*HDIM + h;
    float cold = cBuf[off];                    // own (b,h) slice all kernel: L1-coherent
    float cc = sigmf(fv)*cold + sigmf(iv)*tanhf_fast(gv);
    float hv = sigmf(ov)*tanhf_fast(cc);
    cBuf[off] = cc;
    u16 hb = f2bf(hv);
    hW[off] = hb;
    if (inp_out) inp_out[(size_t)b*512 + d*HDIM + h] = hb;
    if (h_all_t) h_all_t[off] = hv;
  }
}

// ---------------- phase: 6x6 layer-mix for one (b,h) at timestep t ----------------
__device__ __forceinline__ void mix_one(int b, int h, const float* __restrict__ inp,
    float* __restrict__ outp, const float* __restrict__ W2, int t){
  size_t base2 = ((size_t)t*6)*BH + (size_t)b*256 + h;
  float v[6];
  #pragma unroll
  for (int l = 0; l < 6; l++) v[l] = ldfv(&inp[base2 + (size_t)l*BH]);
  #pragma unroll
  for (int m = 0; m < 6; m++){
    float s = 0.f;
    #pragma unroll
    for (int l = 0; l < 6; l++) s += W2[m*6+l]*v[l];
    outp[base2 + (size_t)m*BH] = s;
  }
}

// ---------------- phase: fp32 gemm tile (256 threads per call; conflict-free Ws reads) ----------------
__device__ __forceinline__ void gemm_tile(GmS& sg, int tid, int m_base,
    const float* __restrict__ A, float* __restrict__ C, const float* __restrict__ W,
    const float* __restrict__ bias2d, u16* __restrict__ Cbf){
  int rg = tid >> 5, cg = tid & 31;
  float acc[4][8];
  #pragma unroll
  for (int i=0;i<4;i++)
    #pragma unroll
    for (int j=0;j<8;j++) acc[i][j]=0.f;
  for (int k0 = 0; k0 < 256; k0 += 32){
    #pragma unroll
    for (int p=0;p<4;p++) sg.As[rg + p*8][cg] = ldfv(&A[(size_t)(m_base + rg + p*8)*256 + k0 + cg]);
    #pragma unroll
    for (int p=0;p<32;p++) sg.Ws[rg + p*8][cg] = W[(size_t)(rg + p*8)*256 + k0 + cg];
    __syncthreads();
    #pragma unroll
    for (int kk=0; kk<32; kk++){
      float a[4], w[8];
      #pragma unroll
      for (int i=0;i<4;i++) a[i] = sg.As[rg*4+i][kk];
      #pragma unroll
      for (int j=0;j<8;j++) w[j] = sg.Ws[cg + 32*j][kk];   // stride-34 -> 2-way, free
      #pragma unroll
      for (int i=0;i<4;i++)
        #pragma unroll
        for (int j=0;j<8;j++) acc[i][j] += a[i]*w[j];
    }
    __syncthreads();
  }
  #pragma unroll
  for (int i=0;i<4;i++){
    int row = m_base + rg*4 + i;
    int bm = (row >> 8) % 6;
    #pragma unroll
    for (int j=0;j<8;j++){
      int col = cg + 32*j;
      float v = acc[i][j] + bias2d[bm*256 + col];
      if (C)   C[(size_t)row*256 + col] = v;
      if (Cbf) Cbf[(size_t)row*256 + col] = f2bf(v);
    }
  }
}

// ---------------- phase: attention ctx + fc(prev step) + token embed (512 thr) ----------------
__device__ __forceinline__ void attn_phase(SharedU* shp, int b, int step,
    const u16* __restrict__ hR, const u16* __restrict__ eo, u16* __restrict__ cat,
    const int* __restrict__ tf, float* __restrict__ attn_out,
    const int* __restrict__ target, float* __restrict__ outp,
    const float* __restrict__ dec_emb, const u16* __restrict__ top,
    const float* __restrict__ fc_W, const float* __restrict__ fc_b){
  auto& sf = shp->fc;
  int tid = threadIdx.x;
  if (step > 0){
    sf.s[tid] = ldbfv(&top[(size_t)b*512 + tid]);
    __syncthreads();
    if (tid < 4*VDEC){
      int v = tid >> 2, part = tid & 3;
      int k0 = part*128;
      const float* wr = fc_W + (size_t)v*512;
      float a = 0.f;
      #pragma unroll 4
      for (int k = k0; k < k0+128; k++) a += sf.s[k]*wr[k];
      sf.p4[v][part] = a;
    }
    __syncthreads();
    if (tid < VDEC){
      float a = fc_b[tid] + sf.p4[tid][0] + sf.p4[tid][1] + sf.p4[tid][2] + sf.p4[tid][3];
      outp[((size_t)step*BB + b)*VDEC + tid] = a;
      sf.lg[tid] = a;
    }
    __syncthreads();
  }
  int tok;
  if (tf[0]) tok = target[b*TOUT + step];
  else if (step == 0) tok = 1;
  else {
    if (tid == 0){
      int bi = 0; float bv = sf.lg[0];
      for (int v = 1; v < VDEC; v++){ float x = sf.lg[v]; if (x > bv){ bv = x; bi = v; } }
      sf.tok = bi;
    }
    __syncthreads();
    tok = sf.tok;
  }
  if (tid < 256) cat[(size_t)b*512 + tid] = f2bf(dec_emb[(size_t)tok*EDIM + tid]);
  // ctx: d split across thread halves
  int hc = tid & 255, dhalf = tid >> 8;
  bool wa = (tf[0] == 0);
  float acc = 0.f;
  for (int dd = 0; dd < 3; dd++){
    int d = dhalf*3 + dd;
    float hv = ldbfv(&hR[(size_t)d*BH + (size_t)b*256 + hc]);
    const u16* ep = eo + (size_t)d*BH + (size_t)b*256 + hc;  // eo constant post-bridge: L1 OK
    float se = 0.f, ac = 0.f;
    #pragma unroll 8
    for (int t = 0; t < TIN; t++){
      float ev = bf2f(ep[(size_t)t*(DD*BH)]);
      float e = __expf(hv*ev);
      se += e; ac += e*ev;
    }
    acc += ac/se;
    if (wa){
      float inv = 1.f/se;
      for (int t = 0; t < TIN; t++){
        float ev = bf2f(ep[(size_t)t*(DD*BH)]);
        atomicAdd(&attn_out[(((size_t)(step+1)*TIN + t)*DD + d)*BB + b], __expf(hv*ev)*inv);
      }
    }
  }
  sf.ctxp[dhalf][hc] = acc;
  __syncthreads();
  if (tid < 256)
    cat[(size_t)b*512 + 256 + tid] = f2bf((sf.ctxp[0][tid] + sf.ctxp[1][tid])*(1.0f/6.0f));
}

__device__ __forceinline__ void fc_final_phase(SharedU* shp, int b,
    const u16* __restrict__ top, const float* __restrict__ fc_W,
    const float* __restrict__ fc_b, float* __restrict__ outp){
  auto& sf = shp->fc;
  int tid = threadIdx.x;
  sf.s[tid] = ldbfv(&top[(size_t)b*512 + tid]);
  __syncthreads();
  if (tid < 4*VDEC){
    int v = tid >> 2, part = tid & 3;
    int k0 = part*128;
    const float* wr = fc_W + (size_t)v*512;
    float a = 0.f;
    #pragma unroll 4
    for (int k = k0; k < k0+128; k++) a += sf.s[k]*wr[k];
    sf.p4[v][part] = a;
  }
  __syncthreads();
  if (tid < VDEC){
    float a = fc_b[tid] + sf.p4[tid][0] + sf.p4[tid][1] + sf.p4[tid][2] + sf.p4[tid][3];
    outp[((size_t)(TOUT-1)*BB + b)*VDEC + tid] = a;
  }
}

// ---------------- THE megakernel (512 threads; XCD-local barriers) ----------------
__global__ __launch_bounds__(512, 2) void mega_kernel(
    const int* __restrict__ target, const int* __restrict__ tf,
    const float* __restrict__ dec_emb, const u16* __restrict__ x_emb,
    const u16* __restrict__ wp_e0, const u16* __restrict__ wp_e1, const u16* __restrict__ wp_e2,
    const u16* __restrict__ wp_d0f, const u16* __restrict__ wp_d1, const u16* __restrict__ wp_d2,
    const float* __restrict__ enc_b, const float* __restrict__ dec_b, const float* __restrict__ fb0,
    const float* __restrict__ lin_h_W1, const float* __restrict__ lin_c_W1, const float* __restrict__ lin_a_W1,
    const float* __restrict__ lin_h_W2, const float* __restrict__ lin_c_W2, const float* __restrict__ lin_a_W2,
    const float* __restrict__ bias2d,
    const float* __restrict__ fc_W, const float* __restrict__ fc_b,
    float* __restrict__ out,
    float* __restrict__ h_all, float* __restrict__ tmp6, float* __restrict__ tmp6c,
    float* __restrict__ dec_c, u16* __restrict__ enc_hA, float* __restrict__ enc_c,
    u16* __restrict__ enc_hB, u16* __restrict__ dec_hA, u16* __restrict__ dec_hB,
    u16* __restrict__ bufA, u16* __restrict__ bufB, u16* __restrict__ cat,
    u16* __restrict__ eo_bf, u32* __restrict__ barblk)
{
  __shared__ SharedU sh;
  __shared__ u32 ord_sh;
  const int bid = blockIdx.x, tid = threadIdx.x;
  u32* ctr = barblk + 336;
  u32* badflag = barblk + 352;
  u32 g = 0;

  // ---- mode detect: claim per-XCD ordinal; verify even 32/XCD distribution ----
  u32 xcc;
  asm volatile("s_getreg_b32 %0, hwreg(HW_REG_XCC_ID)" : "=s"(xcc));
  xcc &= 7u;
  if (tid == 0){
    u32 o = __hip_atomic_fetch_add(&ctr[xcc], 1u, __ATOMIC_RELAXED, __HIP_MEMORY_SCOPE_AGENT);
    ord_sh = o;
    if (o >= 32u)
      __hip_atomic_store(badflag, 1u, __ATOMIC_RELAXED, __HIP_MEMORY_SCOPE_AGENT);
  }
  xbar(barblk, 0, ++g, bid, false);   // slow barrier for mode agreement
  bool fast = (__hip_atomic_load(badflag, __ATOMIC_RELAXED, __HIP_MEMORY_SCOPE_AGENT) == 0u);
  int mt, y;
  if (fast){ mt = (int)xcc; y = (int)ord_sh; }
  else     { mt = bid & 7;  y = bid >> 3;    }
  const int half = tid >> 8, htid = tid & 255;
  const int b = mt*32 + y;

  // -------- encoder: 32 timesteps; 2 barriers/step (stage2(t) || stage0(t+1)) --------
  for (int t = 0; t < TIN; t++){
    const u16* hRb = (t & 1) ? enc_hB : enc_hA;
    u16*       hWb = (t & 1) ? enc_hA : enc_hB;
    float* hat = h_all + (size_t)t*DD*BH;
    // stage2 of t-1 ran just before this (no barrier needed: bufA untouched by it)
    stage_phase<256>(&sh, mt, y, x_emb + (size_t)t*BB*EDIM, wp_e0, enc_b,        hRb, hWb, enc_c, bufA, hat, 0);
    xbar(barblk, mt, ++g, bid, fast);
    stage_phase<512>(&sh, mt, y, bufA,                      wp_e1, enc_b + 2048, hRb, hWb, enc_c, bufB, hat, 1);
    xbar(barblk, mt, ++g, bid, fast);
    stage_phase<512>(&sh, mt, y, bufB,                      wp_e2, enc_b + 4096, hRb, hWb, enc_c, nullptr, hat, 2);
  }
  xbar(barblk, mt, ++g, bid, fast);

  // -------- bridges (all XCD-local tile assignments) --------
  {
    if (half == 0) mix_one(b, htid, h_all + (size_t)31*DD*BH, tmp6,  lin_h_W2, 0);
    else           mix_one(b, htid, enc_c,                    tmp6c, lin_c_W2, 0);
    __syncthreads();                               // a-mix below overwrites h_all[31]
    for (int t2 = half*16; t2 < half*16 + 16; t2++)
      mix_one(b, htid, h_all, h_all, lin_a_W2, t2);
  }
  xbar(barblk, mt, ++g, bid, fast);
  // h/c bridge: y=0..5 -> l=y, rows l*256 + mt*32 (XCD-local batch slice)
  if (y < 6){
    if (half == 0) gemm_tile(sh.gm2[0], htid, y*256 + mt*32, tmp6,  nullptr, lin_h_W1, bias2d + 1536, dec_hA);
    else           gemm_tile(sh.gm2[1], htid, y*256 + mt*32, tmp6c, dec_c,   lin_c_W1, bias2d + 3072, nullptr);
  }
  // a-projection: 192 tiles/XCD = 32 y x 6; rows (t*6+l)*256 + mt*32 (XCD-local)
  #pragma unroll
  for (int jj = 0; jj < 3; jj++){
    int k2 = y*6 + half*3 + jj;
    gemm_tile(sh.gm2[half], htid, k2*256 + mt*32, h_all, nullptr, lin_a_W1, bias2d, eo_bf);
  }
  xbar(barblk, mt, ++g, bid, fast);

  // -------- decoder: 28 steps x (attn+fc | stage0 | stage1 | stage2) --------
  float* attn_out = out + (size_t)TOUT*BB*VDEC;
  for (int i = 0; i < TOUT-1; i++){
    const u16* hRb = (i & 1) ? dec_hB : dec_hA;
    u16*       hWb = (i & 1) ? dec_hA : dec_hB;
    attn_phase(&sh, b, i, hRb, eo_bf, cat, tf, attn_out, target, out, dec_emb, bufA, fc_W, fc_b);
    xbar(barblk, mt, ++g, bid, fast);
    stage_phase<512>(&sh, mt, y, cat,  wp_d0f, fb0,          hRb, hWb, dec_c, bufA, nullptr, 0);
    xbar(barblk, mt, ++g, bid, fast);
    stage_phase<512>(&sh, mt, y, bufA, wp_d1,  dec_b + 2048, hRb, hWb, dec_c, bufB, nullptr, 1);
    xbar(barblk, mt, ++g, bid, fast);
    stage_phase<512>(&sh, mt, y, bufB, wp_d2,  dec_b + 4096, hRb, hWb, dec_c, bufA, nullptr, 2);
    xbar(barblk, mt, ++g, bid, fast);
  }
  fc_final_phase(&sh, b, bufA, fc_W, fc_b, out);
}

// =====================================================================

extern "C" void kernel_launch(void* const* d_in, const int* in_sizes, int n_in,
                              void* d_out, int out_size, void* d_ws, size_t ws_size,
                              hipStream_t stream){
  (void)in_sizes; (void)n_in; (void)out_size; (void)ws_size;
  const int*   input    = (const int*)d_in[0];
  const int*   target   = (const int*)d_in[1];
  const int*   tf       = (const int*)d_in[2];
  const float* enc_emb  = (const float*)d_in[3];
  const float* dec_emb  = (const float*)d_in[4];
  const float* enc_Wih0 = (const float*)d_in[5];
  const float* enc_Wih1 = (const float*)d_in[6];
  const float* enc_Whh  = (const float*)d_in[7];
  const float* enc_b    = (const float*)d_in[8];
  const float* dec_Wih0 = (const float*)d_in[9];
  const float* dec_Wih1 = (const float*)d_in[10];
  const float* dec_Whh  = (const float*)d_in[11];
  const float* dec_b    = (const float*)d_in[12];
  const float* lin_h_W1 = (const float*)d_in[13];
  const float* lin_h_b1 = (const float*)d_in[14];
  const float* lin_h_W2 = (const float*)d_in[15];
  const float* lin_h_b2 = (const float*)d_in[16];
  const float* lin_c_W1 = (const float*)d_in[17];
  const float* lin_c_b1 = (const float*)d_in[18];
  const float* lin_c_W2 = (const float*)d_in[19];
  const float* lin_c_b2 = (const float*)d_in[20];
  const float* lin_a_W1 = (const float*)d_in[21];
  const float* lin_a_b1 = (const float*)d_in[22];
  const float* lin_a_W2 = (const float*)d_in[23];
  const float* lin_a_b2 = (const float*)d_in[24];
  const float* attn_W   = (const float*)d_in[25];
  const float* attn_b   = (const float*)d_in[26];
  const float* fc_W     = (const float*)d_in[27];
  const float* fc_b     = (const float*)d_in[28];
  float* out = (float*)d_out;

  char* base = (char*)d_ws;
  size_t off = 0;
  auto alloc = [&](size_t bytes)->char*{
    char* p = base + off; off += (bytes + 255) & ~(size_t)255; return p;
  };
  float* h_all  = (float*)alloc(sizeof(float)*(size_t)TIN*DD*BH);
  float* tmp6   = (float*)alloc(sizeof(float)*(size_t)DD*BH);
  float* tmp6c  = (float*)alloc(sizeof(float)*(size_t)DD*BH);
  float* dec_c  = (float*)alloc(sizeof(float)*(size_t)DD*BH);
  float* bias2d = (float*)alloc(sizeof(float)*3*6*256);
  u16*   enc_hA = (u16*)alloc(sizeof(u16)*(size_t)DD*BH + sizeof(float)*(size_t)DD*BH);
  float* enc_c  = (float*)(enc_hA + (size_t)DD*BH);
  u16* enc_hB = (u16*)alloc(sizeof(u16)*(size_t)DD*BH);
  u16* dec_hA = (u16*)alloc(sizeof(u16)*(size_t)DD*BH);
  u16* dec_hB = (u16*)alloc(sizeof(u16)*(size_t)DD*BH);
  u16* x_emb  = (u16*)alloc(sizeof(u16)*(size_t)TIN*BB*EDIM);
  u16* bufA   = (u16*)alloc(sizeof(u16)*(size_t)BB*512);
  u16* bufB   = (u16*)alloc(sizeof(u16)*(size_t)BB*512);
  u16* cat    = (u16*)alloc(sizeof(u16)*(size_t)BB*512);
  u16* eo_bf  = (u16*)alloc(sizeof(u16)*(size_t)TIN*DD*BH);
  u16* wp_e0  = (u16*)alloc(sizeof(u16)*(size_t)2048*512);
  u16* wp_e1  = (u16*)alloc(sizeof(u16)*(size_t)2048*768);
  u16* wp_e2  = (u16*)alloc(sizeof(u16)*(size_t)2048*768);
  u16* wp_d0f = (u16*)alloc(sizeof(u16)*(size_t)2048*768);
  u16* wp_d1  = (u16*)alloc(sizeof(u16)*(size_t)2048*768);
  u16* wp_d2  = (u16*)alloc(sizeof(u16)*(size_t)2048*768);
  float* fb0  = (float*)alloc(sizeof(float)*2048);
  u32* barblk = (u32*)alloc(sizeof(u32)*1024);

  const int outn = TOUT*BB*VDEC + TOUT*TIN*DD*BB;
  init_out_kernel<<<(outn+255)/256, 256, 0, stream>>>(out, outn);
  fill_zero_u32<<<(DD*BH*6/4 + 255)/256, 256, 0, stream>>>((u32*)enc_hA, DD*BH*6/4);
  fill_zero_u32<<<4, 256, 0, stream>>>(barblk, 1024);
  bias2d_kernel<<<1, 256, 0, stream>>>(lin_a_W2, lin_a_b1, lin_a_b2,
                                       lin_h_W2, lin_h_b1, lin_h_b2,
                                       lin_c_W2, lin_c_b1, lin_c_b2, bias2d);
  embed_enc_kernel<<<(TIN*BB*EDIM)/256, 256, 0, stream>>>(input, enc_emb, x_emb);
  pack_w_kernel<<<dim3(2,2048), 256, 0, stream>>>(enc_Wih0, enc_Whh,                       wp_e0, 256, 512);
  pack_w_kernel<<<dim3(3,2048), 256, 0, stream>>>(enc_Wih1, enc_Whh + 2*1024*256,          wp_e1, 512, 768);
  pack_w_kernel<<<dim3(3,2048), 256, 0, stream>>>(enc_Wih1 + (size_t)2*1024*512, enc_Whh + 4*1024*256, wp_e2, 512, 768);
  pack_wfused_kernel<<<dim3(3,2048), 256, 0, stream>>>(dec_Wih0, attn_W, dec_Whh,          wp_d0f);
  biasfold_kernel<<<8, 256, 0, stream>>>(dec_Wih0, attn_b, dec_b, fb0);
  pack_w_kernel<<<dim3(3,2048), 256, 0, stream>>>(dec_Wih1, dec_Whh + 2*1024*256,          wp_d1, 512, 768);
  pack_w_kernel<<<dim3(3,2048), 256, 0, stream>>>(dec_Wih1 + (size_t)2*1024*512, dec_Whh + 4*1024*256, wp_d2, 512, 768);

  mega_kernel<<<NBLK, 512, 0, stream>>>(
      target, tf, dec_emb, x_emb,
      wp_e0, wp_e1, wp_e2, wp_d0f, wp_d1, wp_d2,
      enc_b, dec_b, fb0,
      lin_h_W1, lin_c_W1, lin_a_W1, lin_h_W2, lin_c_W2, lin_a_W2,
      bias2d, fc_W, fc_b, out,
      h_all, tmp6, tmp6c, dec_c, enc_hA, enc_c, enc_hB, dec_hA, dec_hB,
      bufA, bufB, cat, eo_bf, barblk);
}